// Round 1
// baseline (7523.601 us; speedup 1.0000x reference)
//
#include <hip/hip_runtime.h>
#include <math.h>

#define Bq 4
#define Sq 4096
#define Dq 1024
#define Hq 128
#define Mq 256
#define Rq 64
#define Cq 64
#define NCHUNK 64
#define BSq (Bq*Sq)

__device__ __forceinline__ float softplusf_(float x){
  return fmaxf(x,0.f) + log1pf(expf(-fabsf(x)));
}
__device__ __forceinline__ float sigmoidf_(float x){
  return 1.f/(1.f+expf(-x));
}

// C[M,N] = A[M,K] @ B[K,N]; act: 0 none, 1 softplus, 2 sigmoid, 3 *sigmoid(gate)
// M covered by gridDim.y*64; N, K multiples of 16/64 per launch config.
__global__ __launch_bounds__(256) void gemm_f32(
    const float* __restrict__ A, const float* __restrict__ B,
    float* __restrict__ C, const float* __restrict__ gate,
    int N, int K, int act)
{
  __shared__ float As[16][64];   // [k][m]
  __shared__ float Bs[16][68];   // [k][n] (+pad)
  int tid = threadIdx.x;
  int bm = blockIdx.y*64, bn = blockIdx.x*64;
  int tx = tid & 15, ty = tid >> 4;
  float acc[4][4];
  #pragma unroll
  for (int i=0;i<4;i++){
    #pragma unroll
    for (int j=0;j<4;j++) acc[i][j]=0.f;
  }
  int arow = tid >> 2, acol = (tid & 3)*4;
  int brow = tid >> 4, bcol = (tid & 15)*4;
  for (int k0=0;k0<K;k0+=16){
    #pragma unroll
    for (int j=0;j<4;j++)
      As[acol+j][arow] = A[(size_t)(bm+arow)*K + k0+acol+j];
    #pragma unroll
    for (int j=0;j<4;j++)
      Bs[brow][bcol+j] = B[(size_t)(k0+brow)*N + bn+bcol+j];
    __syncthreads();
    #pragma unroll
    for (int kk=0;kk<16;kk++){
      float a[4], bv[4];
      #pragma unroll
      for (int i=0;i<4;i++) a[i]=As[kk][ty*4+i];
      #pragma unroll
      for (int j=0;j<4;j++) bv[j]=Bs[kk][tx*4+j];
      #pragma unroll
      for (int i=0;i<4;i++){
        #pragma unroll
        for (int j=0;j<4;j++) acc[i][j] += a[i]*bv[j];
      }
    }
    __syncthreads();
  }
  #pragma unroll
  for (int i=0;i<4;i++){
    int row = bm+ty*4+i;
    #pragma unroll
    for (int j=0;j<4;j++){
      int col = bn+tx*4+j;
      float v = acc[i][j];
      if (act==1) v = softplusf_(v);
      else if (act==2) v = sigmoidf_(v);
      else if (act==3) v *= sigmoidf_(gate[(size_t)row*N+col]);
      C[(size_t)row*N+col] = v;
    }
  }
}

// which==0: k path (conv + LN), which==1: v path (conv only)
__global__ __launch_bounds__(128) void conv_ln_kernel(
  const float* __restrict__ k_raw, const float* __restrict__ v_raw,
  const float* __restrict__ conv_w, const float* __restrict__ conv_b,
  const float* __restrict__ kn_g, const float* __restrict__ kn_b,
  float* __restrict__ k_out, float* __restrict__ v_out)
{
  int s = blockIdx.x, b = blockIdx.y, which = blockIdx.z;
  int h = threadIdx.x;
  const float* src = (which==0) ? k_raw : v_raw;
  float acc = conv_b[h];
  #pragma unroll
  for (int j=0;j<4;j++){
    int ss = s-3+j;
    if (ss>=0) acc += conv_w[h*4+j]*src[((size_t)b*Sq+ss)*Hq + h];
  }
  if (which==0){
    __shared__ float red[4];
    float sv = acc, s2 = acc*acc;
    #pragma unroll
    for (int off=32; off>0; off>>=1){
      sv += __shfl_down(sv, off, 64);
      s2 += __shfl_down(s2, off, 64);
    }
    if ((h&63)==0){ red[(h>>6)*2]=sv; red[(h>>6)*2+1]=s2; }
    __syncthreads();
    float mean = (red[0]+red[2])*(1.f/128.f);
    float var  = (red[1]+red[3])*(1.f/128.f) - mean*mean;
    float y = (acc-mean)*rsqrtf(var+1e-5f)*kn_g[h]+kn_b[h];
    k_out[((size_t)b*Sq+s)*Hq + h] = y;
  } else {
    v_out[((size_t)b*Sq+s)*Hq + h] = acc;
  }
}

// W1T[b][h][m] = mW1[m][h]; W2T[b][m][h] = mW2[h][m]
__global__ void init_state(const float* __restrict__ mW1, const float* __restrict__ mW2,
                           float* __restrict__ W1T, float* __restrict__ W2T)
{
  int idx = blockIdx.x*blockDim.x + threadIdx.x;
  if (idx >= Bq*Hq*Mq) return;
  int r = idx & (Hq*Mq - 1);
  int h1 = r >> 8, m1 = r & 255;
  W1T[idx] = mW1[m1*Hq + h1];
  int m2 = r >> 7, h2 = r & 127;
  W2T[idx] = mW2[h2*Mq + m2];
}

__global__ __launch_bounds__(1024) void scan_kernel(
  const float* __restrict__ k_ln, const float* __restrict__ v_c,
  const float* __restrict__ eta, const float* __restrict__ delta,
  const float* __restrict__ alpha,
  const float* __restrict__ mb1, const float* __restrict__ mb2,
  float* __restrict__ W1T, float* __restrict__ W2T,
  float* __restrict__ combined)
{
  __shared__ float Skc[Cq][Hq];      // 32KB; reused as grad buffer after out-phase
  __shared__ float Sact[Cq][64];     // 16KB; one 64-wide m slice of act
  __shared__ float Samp[16][64];     // partial sums for am
  __shared__ float Sam[Mq];
  __shared__ float Sus[Hq];
  __shared__ float Sen[Cq];
  __shared__ float Sb1[Mq];
  __shared__ float Sb2[Hq];
  __shared__ float Sab[Hq];
  __shared__ float Seb[Hq];
  __shared__ float Saw, Sew;

  int b = blockIdx.x;
  int tid = threadIdx.x;
  if (tid < Mq) Sb1[tid] = mb1[tid];
  if (tid < Hq) Sb2[tid] = mb2[tid];
  float* W1Tb = W1T + (size_t)b*Hq*Mq;
  float* W2Tb = W2T + (size_t)b*Mq*Hq;
  const int h_o = tid & 127, cgo = tid >> 7;   // out/err phase: 8 c's per thread
  const int ml_i = tid & 63, cgi = tid >> 6;   // inter phase: 4 c's per thread

  for (int t=0; t<NCHUNK; ++t){
    const float* kb = k_ln + ((size_t)b*Sq + (size_t)t*Cq)*Hq;
    __syncthreads();
    for (int i=tid; i<Cq*Hq; i+=1024) ((float*)Skc)[i] = kb[i];
    if (tid < Hq){
      size_t last = ((size_t)b*Sq + (size_t)t*Cq + 63)*Hq + tid;
      Sab[tid] = alpha[last];
      Seb[tid] = eta[last];
    }
    __syncthreads();
    if (tid==0){
      float s1=0.f, s2=0.f;
      for (int hh=0; hh<Hq; ++hh){ s1+=Sab[hh]; s2+=Seb[hh]; }
      Saw = s1*(1.f/128.f); Sew = s2*(1.f/128.f);
    }

    float outacc[8];
    #pragma unroll
    for (int j=0;j<8;j++) outacc[j]=0.f;

    for (int mb=0; mb<4; ++mb){
      int m = mb*64 + ml_i;
      float ia[4];
      float b1v = Sb1[m];
      #pragma unroll
      for (int j=0;j<4;j++) ia[j]=b1v;
      for (int h2=0; h2<Hq; ++h2){
        float w = W1Tb[(size_t)h2*Mq + m];
        #pragma unroll
        for (int j=0;j<4;j++) ia[j] += Skc[cgi*4+j][h2]*w;
      }
      float av[4]; float asum=0.f;
      #pragma unroll
      for (int j=0;j<4;j++){
        float xg = ia[j];
        float g = 0.5f*xg*(1.f+erff(xg*0.70710678118f));  // exact gelu
        av[j]=g; asum+=g;
      }
      __syncthreads();   // prev mb's Sact readers done
      #pragma unroll
      for (int j=0;j<4;j++) Sact[cgi*4+j][ml_i]=av[j];
      Samp[cgi][ml_i]=asum;
      __syncthreads();
      if (tid<64){
        float s=0.f;
        #pragma unroll
        for (int g2=0; g2<16; ++g2) s += Samp[g2][tid];
        Sam[mb*64+tid] = s*(1.f/64.f);
      }
      for (int ml=0; ml<64; ++ml){
        float w2 = W2Tb[(size_t)(mb*64+ml)*Hq + h_o];
        #pragma unroll
        for (int j=0;j<8;j++) outacc[j] += Sact[cgo*8+j][ml]*w2;
      }
    }
    __syncthreads();   // Sact reads done; Skc now reusable as grad
    {
      const float* vb = v_c + ((size_t)b*Sq + (size_t)t*Cq)*Hq;
      float* cb = combined + ((size_t)b*Sq + (size_t)t*Cq)*Hq;
      #pragma unroll
      for (int j=0;j<8;j++){
        int c = cgo*8+j;
        float o = outacc[j] + Sb2[h_o];
        cb[(size_t)c*Hq + h_o] = o;
        Skc[c][h_o] = o - vb[(size_t)c*Hq + h_o];   // err
      }
    }
    __syncthreads();
    {
      int c = tid >> 4, l = tid & 15;
      float s = 0.f;
      #pragma unroll
      for (int q8=0;q8<8;q8++){ float e = Skc[c][l*8+q8]; s += e*e; }
      #pragma unroll
      for (int off=8; off>0; off>>=1) s += __shfl_down(s, off, 16);
      if (l==0) Sen[c] = sqrtf(s);
    }
    __syncthreads();
    {
      const float* db = delta + ((size_t)b*Sq + (size_t)t*Cq)*Hq;
      #pragma unroll
      for (int j=0;j<8;j++){
        int c = cgo*8+j;
        float e = Skc[c][h_o];
        float en = Sen[c];
        float dv = db[(size_t)c*Hq + h_o];
        Skc[c][h_o] = (en > dv) ? dv*e/(en+1e-9f) : e;   // grad
      }
    }
    __syncthreads();
    if (tid < Hq){
      float s=0.f;
      for (int c=0;c<Cq;c++) s += Skc[c][tid];
      Sus[tid] = s*(1.f/64.f);   // us == b2u
    }
    __syncthreads();
    float aw = Saw, ew = Sew;
    for (int i=tid; i<Hq*Mq; i+=1024){
      int h2 = i >> 8, m = i & 255;
      W1Tb[i] = aw*W1Tb[i] - ew*Sus[h2]*Sam[m];
    }
    for (int i=tid; i<Mq*Hq; i+=1024){
      int m = i >> 7, h2 = i & 127;
      W2Tb[i] = aw*W2Tb[i] - ew*Sus[h2]*Sam[m];
    }
    __syncthreads();   // nW2 visible for b1u
    if (tid < Hq){
      Sb2[tid] = Sab[tid]*Sb2[tid] - Seb[tid]*Sus[tid];
    }
    if (tid >= 128 && tid < 128+Mq){
      int m = tid - 128;
      float s=0.f;
      for (int h2=0; h2<Hq; ++h2) s += Sus[h2]*W2Tb[(size_t)m*Hq + h2];
      Sb1[m] = aw*Sb1[m] - ew*s;   // nb1 = aw*b1 - ew*b1u  (ab.mean==aw, eb.mean==ew)
    }
  }
}

extern "C" void kernel_launch(void* const* d_in, const int* in_sizes, int n_in,
                              void* d_out, int out_size, void* d_ws, size_t ws_size,
                              hipStream_t stream)
{
  const float* x    = (const float*)d_in[0];
  // d_in[1] = Wq: dead code in reference (q never used) — skipped.
  const float* Wk   = (const float*)d_in[2];
  const float* Wv   = (const float*)d_in[3];
  const float* Wo   = (const float*)d_in[4];
  const float* Wg   = (const float*)d_in[5];
  const float* We1  = (const float*)d_in[6];
  const float* We2  = (const float*)d_in[7];
  const float* Wd1  = (const float*)d_in[8];
  const float* Wd2  = (const float*)d_in[9];
  const float* Wa1  = (const float*)d_in[10];
  const float* Wa2  = (const float*)d_in[11];
  const float* conv_w = (const float*)d_in[12];
  const float* conv_b = (const float*)d_in[13];
  // d_in[14],[15] = qn_g/qn_b: dead (q path). 
  const float* kn_g = (const float*)d_in[16];
  const float* kn_b = (const float*)d_in[17];
  const float* mW1  = (const float*)d_in[18];
  const float* mb1  = (const float*)d_in[19];
  const float* mW2  = (const float*)d_in[20];
  const float* mb2  = (const float*)d_in[21];
  float* out = (float*)d_out;

  float* ws = (float*)d_ws;
  size_t o = 0;
  float* k_raw = ws + o; o += (size_t)BSq*Hq;
  float* v_raw = ws + o; o += (size_t)BSq*Hq;
  float* te    = ws + o; o += (size_t)BSq*Rq;
  float* td    = ws + o; o += (size_t)BSq*Rq;
  float* ta    = ws + o; o += (size_t)BSq*Rq;
  float* glog  = ws + o; o += (size_t)BSq*Dq;
  float* etab  = ws + o; o += (size_t)BSq*Hq;
  float* deltab= ws + o; o += (size_t)BSq*Hq;
  float* alphab= ws + o; o += (size_t)BSq*Hq;
  float* k_ln  = ws + o; o += (size_t)BSq*Hq;
  float* v_c   = ws + o; o += (size_t)BSq*Hq;
  float* comb  = ws + o; o += (size_t)BSq*Hq;
  float* W1T   = ws + o; o += (size_t)Bq*Hq*Mq;
  float* W2T   = ws + o; o += (size_t)Bq*Mq*Hq;

  dim3 blk(256);
  // projections
  gemm_f32<<<dim3(Hq/64, BSq/64), blk, 0, stream>>>(x, Wk, k_raw, nullptr, Hq, Dq, 0);
  gemm_f32<<<dim3(Hq/64, BSq/64), blk, 0, stream>>>(x, Wv, v_raw, nullptr, Hq, Dq, 0);
  gemm_f32<<<dim3(Rq/64, BSq/64), blk, 0, stream>>>(x, We1, te, nullptr, Rq, Dq, 0);
  gemm_f32<<<dim3(Rq/64, BSq/64), blk, 0, stream>>>(x, Wd1, td, nullptr, Rq, Dq, 0);
  gemm_f32<<<dim3(Rq/64, BSq/64), blk, 0, stream>>>(x, Wa1, ta, nullptr, Rq, Dq, 0);
  gemm_f32<<<dim3(Dq/64, BSq/64), blk, 0, stream>>>(x, Wg, glog, nullptr, Dq, Dq, 0);
  gemm_f32<<<dim3(Hq/64, BSq/64), blk, 0, stream>>>(te, We2, etab,  nullptr, Hq, Rq, 1);
  gemm_f32<<<dim3(Hq/64, BSq/64), blk, 0, stream>>>(td, Wd2, deltab,nullptr, Hq, Rq, 1);
  gemm_f32<<<dim3(Hq/64, BSq/64), blk, 0, stream>>>(ta, Wa2, alphab,nullptr, Hq, Rq, 2);
  // conv + LN for k, conv for v
  conv_ln_kernel<<<dim3(Sq, Bq, 2), dim3(128), 0, stream>>>(
      k_raw, v_raw, conv_w, conv_b, kn_g, kn_b, k_ln, v_c);
  // state init + sequential scan
  int tot = Bq*Hq*Mq;
  init_state<<<(tot+255)/256, 256, 0, stream>>>(mW1, mW2, W1T, W2T);
  scan_kernel<<<Bq, 1024, 0, stream>>>(k_ln, v_c, etab, deltab, alphab,
                                       mb1, mb2, W1T, W2T, comb);
  // final: (combined @ Wo) * sigmoid(glog)
  gemm_f32<<<dim3(Dq/64, BSq/64), blk, 0, stream>>>(comb, Wo, out, glog, Dq, Hq, 3);
}

// Round 2
// 3232.737 us; speedup vs baseline: 2.3273x; 2.3273x over previous
//
#include <hip/hip_runtime.h>
#include <math.h>

#define Bq 4
#define Sq 4096
#define Dq 1024
#define Hq 128
#define Mq 256
#define Rq 64
#define Cq 64
#define NCHUNK 64
#define BSq (Bq*Sq)

typedef __attribute__((ext_vector_type(8))) short short8;
typedef __attribute__((ext_vector_type(4))) float f32x4;

__device__ __forceinline__ float softplusf_(float x){
  return fmaxf(x,0.f) + log1pf(expf(-fabsf(x)));
}
__device__ __forceinline__ float sigmoidf_(float x){
  return 1.f/(1.f+expf(-x));
}
__device__ __forceinline__ unsigned short bf16rn(float x){
  unsigned u = __float_as_uint(x);
  u += 0x7fffu + ((u>>16)&1u);
  return (unsigned short)(u>>16);
}
__device__ __forceinline__ float bf16tof(unsigned short s){
  return __uint_as_float(((unsigned)s)<<16);
}

// C[M,N] = A[M,K] @ B[K,N]; act: 0 none, 1 softplus, 2 sigmoid, 3 *sigmoid(gate)
__global__ __launch_bounds__(256) void gemm_f32(
    const float* __restrict__ A, const float* __restrict__ B,
    float* __restrict__ C, const float* __restrict__ gate,
    int N, int K, int act)
{
  __shared__ float As[16][64];
  __shared__ float Bs[16][68];
  int tid = threadIdx.x;
  int bm = blockIdx.y*64, bn = blockIdx.x*64;
  int tx = tid & 15, ty = tid >> 4;
  float acc[4][4];
  #pragma unroll
  for (int i=0;i<4;i++){
    #pragma unroll
    for (int j=0;j<4;j++) acc[i][j]=0.f;
  }
  int arow = tid >> 2, acol = (tid & 3)*4;
  int brow = tid >> 4, bcol = (tid & 15)*4;
  for (int k0=0;k0<K;k0+=16){
    #pragma unroll
    for (int j=0;j<4;j++)
      As[acol+j][arow] = A[(size_t)(bm+arow)*K + k0+acol+j];
    #pragma unroll
    for (int j=0;j<4;j++)
      Bs[brow][bcol+j] = B[(size_t)(k0+brow)*N + bn+bcol+j];
    __syncthreads();
    #pragma unroll
    for (int kk=0;kk<16;kk++){
      float a[4], bv[4];
      #pragma unroll
      for (int i=0;i<4;i++) a[i]=As[kk][ty*4+i];
      #pragma unroll
      for (int j=0;j<4;j++) bv[j]=Bs[kk][tx*4+j];
      #pragma unroll
      for (int i=0;i<4;i++){
        #pragma unroll
        for (int j=0;j<4;j++) acc[i][j] += a[i]*bv[j];
      }
    }
    __syncthreads();
  }
  #pragma unroll
  for (int i=0;i<4;i++){
    int row = bm+ty*4+i;
    #pragma unroll
    for (int j=0;j<4;j++){
      int col = bn+tx*4+j;
      float v = acc[i][j];
      if (act==1) v = softplusf_(v);
      else if (act==2) v = sigmoidf_(v);
      else if (act==3) v *= sigmoidf_(gate[(size_t)row*N+col]);
      C[(size_t)row*N+col] = v;
    }
  }
}

__global__ __launch_bounds__(128) void conv_ln_kernel(
  const float* __restrict__ k_raw, const float* __restrict__ v_raw,
  const float* __restrict__ conv_w, const float* __restrict__ conv_b,
  const float* __restrict__ kn_g, const float* __restrict__ kn_b,
  float* __restrict__ k_out, float* __restrict__ v_out)
{
  int s = blockIdx.x, b = blockIdx.y, which = blockIdx.z;
  int h = threadIdx.x;
  const float* src = (which==0) ? k_raw : v_raw;
  float acc = conv_b[h];
  #pragma unroll
  for (int j=0;j<4;j++){
    int ss = s-3+j;
    if (ss>=0) acc += conv_w[h*4+j]*src[((size_t)b*Sq+ss)*Hq + h];
  }
  if (which==0){
    __shared__ float red[4];
    float sv = acc, s2 = acc*acc;
    #pragma unroll
    for (int off=32; off>0; off>>=1){
      sv += __shfl_down(sv, off, 64);
      s2 += __shfl_down(s2, off, 64);
    }
    if ((h&63)==0){ red[(h>>6)*2]=sv; red[(h>>6)*2+1]=s2; }
    __syncthreads();
    float mean = (red[0]+red[2])*(1.f/128.f);
    float var  = (red[1]+red[3])*(1.f/128.f) - mean*mean;
    float y = (acc-mean)*rsqrtf(var+1e-5f)*kn_g[h]+kn_b[h];
    k_out[((size_t)b*Sq+s)*Hq + h] = y;
  } else {
    v_out[((size_t)b*Sq+s)*Hq + h] = acc;
  }
}

// MFMA scan: 1 block/batch, 512 thr (8 waves). State W1/W2 register-resident as
// MFMA B-fragments (fp32 masters, bf16 hi/lo split per use -> fp32-class accuracy).
// Wave w owns: W1 m-tiles {2w,2w+1} (B[k=h][n=m]), W2 h-tile w (B[k=m][n=h]).
// 16x16x32 layouts: A[i=lane&15][k=q*8+j], B[k=q*8+j][n=lane&15],
//                   C/D[row=q*4+r][col=lane&15] (q=lane>>4).
__global__ __launch_bounds__(512, 2) void scan_mfma(
  const float* __restrict__ k_ln, const float* __restrict__ v_c,
  const float* __restrict__ eta, const float* __restrict__ delta,
  const float* __restrict__ alpha,
  const float* __restrict__ mW1, const float* __restrict__ mb1,
  const float* __restrict__ mW2, const float* __restrict__ mb2,
  float* __restrict__ combined)
{
  __shared__ __align__(16) unsigned short kc_hi[Cq*Hq];
  __shared__ __align__(16) unsigned short kc_lo[Cq*Hq];
  __shared__ __align__(16) unsigned short act_hi[Cq*Mq];
  __shared__ __align__(16) unsigned short act_lo[Cq*Mq];
  __shared__ float Sam[Mq], Sus[Hq], Sb1[Mq], Sb2[Hq];
  __shared__ float Sab[Hq], Seb[Hq], Sen[Cq];
  __shared__ float pen[8][Cq];
  __shared__ float pb1u[8][Mq];
  __shared__ float Saw, Sew;

  const int b = blockIdx.x;
  const int tid = threadIdx.x;
  const int wv = tid >> 6;
  const int lane = tid & 63;
  const int n = lane & 15;
  const int q = lane >> 4;

  // ---- load state masters into registers ----
  float w1m[2][4][8];  // W1[m=(2wv+t)*16+n][h=ks*32+q*8+j]
  float w2m[8][8];     // W2[h=wv*16+n][m=ks2*32+q*8+j]
  #pragma unroll
  for (int tt=0;tt<2;tt++){
    int m = (2*wv+tt)*16 + n;
    #pragma unroll
    for (int ks=0;ks<4;ks++){
      const float* p = mW1 + (size_t)m*Hq + ks*32 + q*8;
      #pragma unroll
      for (int j=0;j<8;j++) w1m[tt][ks][j] = p[j];
    }
  }
  {
    int h = wv*16 + n;
    #pragma unroll
    for (int ks2=0;ks2<8;ks2++){
      const float* p = mW2 + (size_t)h*Mq + ks2*32 + q*8;
      #pragma unroll
      for (int j=0;j<8;j++) w2m[ks2][j] = p[j];
    }
  }
  if (tid < Mq) Sb1[tid] = mb1[tid];
  if (tid < Hq) Sb2[tid] = mb2[tid];

  for (int t=0; t<NCHUNK; ++t){
    __syncthreads();   // protect LDS (kc/act/Sab/Sb1/Sb2) across chunks
    // ---- P0: stage kc chunk -> LDS bf16 hi/lo, XOR-swizzled rows ----
    {
      const float* kcg = k_ln + ((size_t)b*Sq + (size_t)t*Cq)*Hq;
      #pragma unroll
      for (int r4=0;r4<4;r4++){
        int idx4 = tid + 512*r4;         // 2048 float4s = 64x128
        int c  = idx4 >> 5;
        int h0 = (idx4 & 31) << 2;
        const float4* pv = (const float4*)(kcg + (size_t)c*Hq + h0);
        float4 v = *pv;
        int pg  = (h0>>3) ^ (c & 15);
        int off = c*Hq + (pg<<3) + (h0&7);
        unsigned short h0s=bf16rn(v.x), h1s=bf16rn(v.y), h2s=bf16rn(v.z), h3s=bf16rn(v.w);
        unsigned short l0s=bf16rn(v.x-bf16tof(h0s)), l1s=bf16rn(v.y-bf16tof(h1s));
        unsigned short l2s=bf16rn(v.z-bf16tof(h2s)), l3s=bf16rn(v.w-bf16tof(h3s));
        *(unsigned*)&kc_hi[off]   = (unsigned)h0s | ((unsigned)h1s<<16);
        *(unsigned*)&kc_hi[off+2] = (unsigned)h2s | ((unsigned)h3s<<16);
        *(unsigned*)&kc_lo[off]   = (unsigned)l0s | ((unsigned)l1s<<16);
        *(unsigned*)&kc_lo[off+2] = (unsigned)l2s | ((unsigned)l3s<<16);
      }
      if (tid < Hq){
        size_t last = ((size_t)b*Sq + (size_t)t*Cq + 63)*Hq + tid;
        Sab[tid] = alpha[last];
        Seb[tid] = eta[last];
      }
    }
    __syncthreads();

    // aw/ew scalars (wave 0)
    if (tid < 64){
      float a2 = Sab[tid] + Sab[tid+64];
      float e2 = Seb[tid] + Seb[tid+64];
      #pragma unroll
      for (int mk=1;mk<64;mk<<=1){ a2 += __shfl_xor(a2,mk,64); e2 += __shfl_xor(e2,mk,64); }
      if (tid==0){ Saw = a2*(1.f/128.f); Sew = e2*(1.f/128.f); }
    }

    // ---- P1: GEMM1 inter = kc @ W1^T (hi/lo, 3 MFMAs) ----
    f32x4 acc[2][4];
    #pragma unroll
    for (int tt=0;tt<2;tt++){
      #pragma unroll
      for (int ct=0;ct<4;ct++){ f32x4 z = {0.f,0.f,0.f,0.f}; acc[tt][ct]=z; }
    }
    #pragma unroll
    for (int ks=0;ks<4;ks++){
      short8 ah[4], al[4];
      #pragma unroll
      for (int ct=0;ct<4;ct++){
        int c = ct*16 + n;
        int pg = (ks*4 + q) ^ n;
        int off = c*Hq + (pg<<3);
        ah[ct] = *(const short8*)&kc_hi[off];
        al[ct] = *(const short8*)&kc_lo[off];
      }
      #pragma unroll
      for (int tt=0;tt<2;tt++){
        short8 bh, bl;
        #pragma unroll
        for (int j=0;j<8;j++){
          float x = w1m[tt][ks][j];
          unsigned short hs = bf16rn(x);
          bh[j] = (short)hs;
          bl[j] = (short)bf16rn(x - bf16tof(hs));
        }
        #pragma unroll
        for (int ct=0;ct<4;ct++)
          acc[tt][ct] = __builtin_amdgcn_mfma_f32_16x16x32_bf16(ah[ct], bh, acc[tt][ct], 0,0,0);
        #pragma unroll
        for (int ct=0;ct<4;ct++)
          acc[tt][ct] = __builtin_amdgcn_mfma_f32_16x16x32_bf16(al[ct], bh, acc[tt][ct], 0,0,0);
        #pragma unroll
        for (int ct=0;ct<4;ct++)
          acc[tt][ct] = __builtin_amdgcn_mfma_f32_16x16x32_bf16(ah[ct], bl, acc[tt][ct], 0,0,0);
      }
    }
    // gelu -> act (LDS hi/lo) + am
    #pragma unroll
    for (int tt=0;tt<2;tt++){
      int m = (2*wv+tt)*16 + n;
      float b1v = Sb1[m];
      float amsum = 0.f;
      #pragma unroll
      for (int ct=0;ct<4;ct++){
        #pragma unroll
        for (int r=0;r<4;r++){
          float xg = acc[tt][ct][r] + b1v;
          float g = 0.5f*xg*(1.f+erff(xg*0.70710678118f));
          amsum += g;
          int c = ct*16 + q*4 + r;
          int pg = (m>>3) ^ (c & 15);
          int off = c*Mq + (pg<<3) + (m&7);
          unsigned short hs = bf16rn(g);
          act_hi[off] = hs;
          act_lo[off] = bf16rn(g - bf16tof(hs));
        }
      }
      amsum += __shfl_xor(amsum, 16, 64);
      amsum += __shfl_xor(amsum, 32, 64);
      if (q==0) Sam[m] = amsum*(1.f/64.f);
    }
    __syncthreads();

    // ---- P3: GEMM2 out = act @ W2^T ----
    f32x4 acc2[4];
    #pragma unroll
    for (int ct=0;ct<4;ct++){ f32x4 z = {0.f,0.f,0.f,0.f}; acc2[ct]=z; }
    #pragma unroll
    for (int ks2=0;ks2<8;ks2++){
      short8 ah[4], al[4];
      #pragma unroll
      for (int ct=0;ct<4;ct++){
        int c = ct*16 + n;
        int pg = (ks2*4 + q) ^ n;
        int off = c*Mq + (pg<<3);
        ah[ct] = *(const short8*)&act_hi[off];
        al[ct] = *(const short8*)&act_lo[off];
      }
      short8 bh, bl;
      #pragma unroll
      for (int j=0;j<8;j++){
        float x = w2m[ks2][j];
        unsigned short hs = bf16rn(x);
        bh[j] = (short)hs;
        bl[j] = (short)bf16rn(x - bf16tof(hs));
      }
      #pragma unroll
      for (int ct=0;ct<4;ct++)
        acc2[ct] = __builtin_amdgcn_mfma_f32_16x16x32_bf16(ah[ct], bh, acc2[ct], 0,0,0);
      #pragma unroll
      for (int ct=0;ct<4;ct++)
        acc2[ct] = __builtin_amdgcn_mfma_f32_16x16x32_bf16(al[ct], bh, acc2[ct], 0,0,0);
      #pragma unroll
      for (int ct=0;ct<4;ct++)
        acc2[ct] = __builtin_amdgcn_mfma_f32_16x16x32_bf16(ah[ct], bl, acc2[ct], 0,0,0);
    }
    // out, combined write, err, en partials
    float err[4][4];
    {
      int h = wv*16 + n;
      float b2v = Sb2[h];
      const float* vb = v_c + ((size_t)b*Sq + (size_t)t*Cq)*Hq;
      float* cb = combined + ((size_t)b*Sq + (size_t)t*Cq)*Hq;
      #pragma unroll
      for (int ct=0;ct<4;ct++){
        #pragma unroll
        for (int r=0;r<4;r++){
          int c = ct*16 + q*4 + r;
          float o = acc2[ct][r] + b2v;
          cb[(size_t)c*Hq + h] = o;
          err[ct][r] = o - vb[(size_t)c*Hq + h];
        }
      }
      #pragma unroll
      for (int ct=0;ct<4;ct++){
        #pragma unroll
        for (int r=0;r<4;r++){
          float s = err[ct][r]*err[ct][r];
          s += __shfl_xor(s,1,64); s += __shfl_xor(s,2,64);
          s += __shfl_xor(s,4,64); s += __shfl_xor(s,8,64);
          if (n==0) pen[wv][ct*16+q*4+r] = s;
        }
      }
    }
    __syncthreads();
    if (tid < Cq){
      float s = 0.f;
      #pragma unroll
      for (int w2=0;w2<8;w2++) s += pen[w2][tid];
      Sen[tid] = sqrtf(s);
    }
    __syncthreads();
    // ---- P7: grad + us ----
    {
      int h = wv*16 + n;
      const float* db = delta + ((size_t)b*Sq + (size_t)t*Cq)*Hq;
      float uss = 0.f;
      #pragma unroll
      for (int ct=0;ct<4;ct++){
        #pragma unroll
        for (int r=0;r<4;r++){
          int c = ct*16 + q*4 + r;
          float en = Sen[c];
          float dv = db[(size_t)c*Hq + h];
          float e = err[ct][r];
          float g = (en > dv) ? dv*e/(en+1e-9f) : e;
          err[ct][r] = g;
          uss += g;
        }
      }
      uss += __shfl_xor(uss,16,64);
      uss += __shfl_xor(uss,32,64);
      if (q==0) Sus[h] = uss*(1.f/64.f);
    }
    __syncthreads();
    // ---- P9: state updates (registers) + b1u partials + b2 ----
    {
      float aw = Saw, ew = Sew;
      #pragma unroll
      for (int tt=0;tt<2;tt++){
        int m = (2*wv+tt)*16 + n;
        float eam = ew*Sam[m];
        #pragma unroll
        for (int ks=0;ks<4;ks++){
          #pragma unroll
          for (int j=0;j<8;j++){
            int h = ks*32 + q*8 + j;
            w1m[tt][ks][j] = aw*w1m[tt][ks][j] - eam*Sus[h];
          }
        }
      }
      int h = wv*16 + n;
      float ush = Sus[h];
      float eus = ew*ush;
      #pragma unroll
      for (int ks2=0;ks2<8;ks2++){
        #pragma unroll
        for (int j=0;j<8;j++){
          int m = ks2*32 + q*8 + j;
          w2m[ks2][j] = aw*w2m[ks2][j] - eus*Sam[m];
        }
      }
      // b1u[m] = sum_h us[h]*nW2[h][m]: reduce over n within quad, partial per wave
      #pragma unroll
      for (int ks2=0;ks2<8;ks2++){
        float s8[8];
        #pragma unroll
        for (int j=0;j<8;j++) s8[j] = ush*w2m[ks2][j];
        #pragma unroll
        for (int mk=1;mk<16;mk<<=1){
          #pragma unroll
          for (int j=0;j<8;j++) s8[j] += __shfl_xor(s8[j], mk, 64);
        }
        if (n==0){
          #pragma unroll
          for (int j=0;j<8;j++) pb1u[wv][ks2*32 + q*8 + j] = s8[j];
        }
      }
      if (tid < Hq) Sb2[tid] = Sab[tid]*Sb2[tid] - Seb[tid]*Sus[tid];
    }
    __syncthreads();
    if (tid < Mq){
      float s=0.f;
      #pragma unroll
      for (int w2=0;w2<8;w2++) s += pb1u[w2][tid];
      Sb1[tid] = Saw*Sb1[tid] - Sew*s;
    }
  }
}

extern "C" void kernel_launch(void* const* d_in, const int* in_sizes, int n_in,
                              void* d_out, int out_size, void* d_ws, size_t ws_size,
                              hipStream_t stream)
{
  const float* x    = (const float*)d_in[0];
  // d_in[1] = Wq: dead code (q never used). d_in[14],[15] = qn_g/qn_b: dead.
  const float* Wk   = (const float*)d_in[2];
  const float* Wv   = (const float*)d_in[3];
  const float* Wo   = (const float*)d_in[4];
  const float* Wg   = (const float*)d_in[5];
  const float* We1  = (const float*)d_in[6];
  const float* We2  = (const float*)d_in[7];
  const float* Wd1  = (const float*)d_in[8];
  const float* Wd2  = (const float*)d_in[9];
  const float* Wa1  = (const float*)d_in[10];
  const float* Wa2  = (const float*)d_in[11];
  const float* conv_w = (const float*)d_in[12];
  const float* conv_b = (const float*)d_in[13];
  const float* kn_g = (const float*)d_in[16];
  const float* kn_b = (const float*)d_in[17];
  const float* mW1  = (const float*)d_in[18];
  const float* mb1  = (const float*)d_in[19];
  const float* mW2  = (const float*)d_in[20];
  const float* mb2  = (const float*)d_in[21];
  float* out = (float*)d_out;

  float* ws = (float*)d_ws;
  size_t o = 0;
  float* k_raw = ws + o; o += (size_t)BSq*Hq;
  float* v_raw = ws + o; o += (size_t)BSq*Hq;
  float* te    = ws + o; o += (size_t)BSq*Rq;
  float* td    = ws + o; o += (size_t)BSq*Rq;
  float* ta    = ws + o; o += (size_t)BSq*Rq;
  float* glog  = ws + o; o += (size_t)BSq*Dq;
  float* etab  = ws + o; o += (size_t)BSq*Hq;
  float* deltab= ws + o; o += (size_t)BSq*Hq;
  float* alphab= ws + o; o += (size_t)BSq*Hq;
  float* k_ln  = ws + o; o += (size_t)BSq*Hq;
  float* v_c   = ws + o; o += (size_t)BSq*Hq;
  float* comb  = ws + o; o += (size_t)BSq*Hq;

  dim3 blk(256);
  gemm_f32<<<dim3(Hq/64, BSq/64), blk, 0, stream>>>(x, Wk, k_raw, nullptr, Hq, Dq, 0);
  gemm_f32<<<dim3(Hq/64, BSq/64), blk, 0, stream>>>(x, Wv, v_raw, nullptr, Hq, Dq, 0);
  gemm_f32<<<dim3(Rq/64, BSq/64), blk, 0, stream>>>(x, We1, te, nullptr, Rq, Dq, 0);
  gemm_f32<<<dim3(Rq/64, BSq/64), blk, 0, stream>>>(x, Wd1, td, nullptr, Rq, Dq, 0);
  gemm_f32<<<dim3(Rq/64, BSq/64), blk, 0, stream>>>(x, Wa1, ta, nullptr, Rq, Dq, 0);
  gemm_f32<<<dim3(Dq/64, BSq/64), blk, 0, stream>>>(x, Wg, glog, nullptr, Dq, Dq, 0);
  gemm_f32<<<dim3(Hq/64, BSq/64), blk, 0, stream>>>(te, We2, etab,  nullptr, Hq, Rq, 1);
  gemm_f32<<<dim3(Hq/64, BSq/64), blk, 0, stream>>>(td, Wd2, deltab,nullptr, Hq, Rq, 1);
  gemm_f32<<<dim3(Hq/64, BSq/64), blk, 0, stream>>>(ta, Wa2, alphab,nullptr, Hq, Rq, 2);
  conv_ln_kernel<<<dim3(Sq, Bq, 2), dim3(128), 0, stream>>>(
      k_raw, v_raw, conv_w, conv_b, kn_g, kn_b, k_ln, v_c);
  scan_mfma<<<Bq, 512, 0, stream>>>(k_ln, v_c, etab, deltab, alphab,
                                    mW1, mb1, mW2, mb2, comb);
  gemm_f32<<<dim3(Dq/64, BSq/64), blk, 0, stream>>>(comb, Wo, out, glog, Dq, Hq, 3);
}

// Round 3
// 2572.393 us; speedup vs baseline: 2.9247x; 1.2567x over previous
//
#include <hip/hip_runtime.h>
#include <math.h>

#define Bq 4
#define Sq 4096
#define Dq 1024
#define Hq 128
#define Mq 256
#define Rq 64
#define Cq 64
#define NCHUNK 64
#define BSq (Bq*Sq)

typedef __attribute__((ext_vector_type(8))) short short8;
typedef __attribute__((ext_vector_type(4))) float f32x4;

__device__ __forceinline__ float softplusf_(float x){
  return fmaxf(x,0.f) + log1pf(expf(-fabsf(x)));
}
__device__ __forceinline__ float sigmoidf_(float x){
  return 1.f/(1.f+__expf(-x));
}
__device__ __forceinline__ unsigned short bf16rn(float x){
  unsigned u = __float_as_uint(x);
  u += 0x7fffu + ((u>>16)&1u);
  return (unsigned short)(u>>16);
}
__device__ __forceinline__ float bf16tof(unsigned short s){
  return __uint_as_float(((unsigned)s)<<16);
}
// exact-gelu via branchless erf (A&S 7.1.26, |err|<=1.5e-7), hw exp
__device__ __forceinline__ float gelu_fast(float x){
  float z  = x*0.70710678118f;
  float az = fabsf(z);
  float t  = __builtin_amdgcn_rcpf(fmaf(0.3275911f, az, 1.f));
  float p  = fmaf(t, 1.061405429f, -1.453152027f);
  p = fmaf(t, p, 1.421413741f);
  p = fmaf(t, p, -0.284496736f);
  p = fmaf(t, p, 0.254829592f);
  p = p*t;
  float e  = __expf(-az*az);
  float er = copysignf(1.f - p*e, z);
  return 0.5f*x*(1.f + er);
}

// ---------------- bf16x3 MFMA GEMM ----------------
// C[M,N] = A[M,K](fp32, split in-kernel) @ B (pre-split bf16 hi/lo, TRANSPOSED [N][K]).
// 3-MFMA hi/lo scheme -> fp32-class accuracy. BM=128, BK=32, BN in {64,128}.
// ACT: 0 none, 1 softplus, 2 sigmoid, 3 *sigmoid(gate)
template<int BN, int ACT>
__global__ __launch_bounds__(256) void gemm_bf3(
    const float* __restrict__ Af,
    const unsigned short* __restrict__ BhT, const unsigned short* __restrict__ BlT,
    float* __restrict__ C, const float* __restrict__ gate, int N, int K)
{
  constexpr int BM = 128;
  constexpr int PK = 40;               // padded LDS row stride (elems), <=2-way banks
  constexpr int TN = BN/32;            // 16-wide n-tiles per wave
  __shared__ __align__(16) unsigned short As[2][BM*PK];
  __shared__ __align__(16) unsigned short Bs[2][BN*PK];
  const int tid = threadIdx.x;
  const int bm = blockIdx.y*BM, bn = blockIdx.x*BN;
  const int wv = tid>>6, lane = tid&63;
  const int n16 = lane&15, q = lane>>4;
  const int wm = wv>>1, wn = wv&1;

  f32x4 acc[4][TN];
  #pragma unroll
  for (int i=0;i<4;i++){
    #pragma unroll
    for (int j=0;j<TN;j++){ f32x4 z={0.f,0.f,0.f,0.f}; acc[i][j]=z; }
  }

  for (int k0=0;k0<K;k0+=32){
    // stage A: fp32 -> bf16 hi/lo
    #pragma unroll
    for (int c0=0;c0<BM*8;c0+=256){
      int c = c0 + tid;
      int row = c>>3, kg = (c&7)*4;
      float4 v = *(const float4*)&Af[(size_t)(bm+row)*K + k0+kg];
      unsigned short h0=bf16rn(v.x),h1=bf16rn(v.y),h2=bf16rn(v.z),h3=bf16rn(v.w);
      unsigned short l0=bf16rn(v.x-bf16tof(h0)),l1=bf16rn(v.y-bf16tof(h1));
      unsigned short l2=bf16rn(v.z-bf16tof(h2)),l3=bf16rn(v.w-bf16tof(h3));
      int off = row*PK+kg;
      *(unsigned*)&As[0][off]   = (unsigned)h0 | ((unsigned)h1<<16);
      *(unsigned*)&As[0][off+2] = (unsigned)h2 | ((unsigned)h3<<16);
      *(unsigned*)&As[1][off]   = (unsigned)l0 | ((unsigned)l1<<16);
      *(unsigned*)&As[1][off+2] = (unsigned)l2 | ((unsigned)l3<<16);
    }
    // stage B: pre-split bf16, 16B copies
    #pragma unroll
    for (int c0=0;c0<BN*4;c0+=256){
      int c = c0 + tid;
      int row = c>>2, kg = (c&3)*8;
      *(short8*)&Bs[0][row*PK+kg] = *(const short8*)&BhT[(size_t)(bn+row)*K + k0+kg];
      *(short8*)&Bs[1][row*PK+kg] = *(const short8*)&BlT[(size_t)(bn+row)*K + k0+kg];
    }
    __syncthreads();
    short8 a_h[4], a_l[4], b_h[TN], b_l[TN];
    #pragma unroll
    for (int i=0;i<4;i++){
      int r = wm*64 + i*16 + n16;
      a_h[i] = *(const short8*)&As[0][r*PK + q*8];
      a_l[i] = *(const short8*)&As[1][r*PK + q*8];
    }
    #pragma unroll
    for (int j=0;j<TN;j++){
      int r = wn*(BN/2) + j*16 + n16;
      b_h[j] = *(const short8*)&Bs[0][r*PK + q*8];
      b_l[j] = *(const short8*)&Bs[1][r*PK + q*8];
    }
    #pragma unroll
    for (int i=0;i<4;i++){
      #pragma unroll
      for (int j=0;j<TN;j++){
        acc[i][j] = __builtin_amdgcn_mfma_f32_16x16x32_bf16(a_h[i], b_h[j], acc[i][j], 0,0,0);
        acc[i][j] = __builtin_amdgcn_mfma_f32_16x16x32_bf16(a_l[i], b_h[j], acc[i][j], 0,0,0);
        acc[i][j] = __builtin_amdgcn_mfma_f32_16x16x32_bf16(a_h[i], b_l[j], acc[i][j], 0,0,0);
      }
    }
    __syncthreads();
  }
  #pragma unroll
  for (int i=0;i<4;i++){
    #pragma unroll
    for (int j=0;j<TN;j++){
      #pragma unroll
      for (int r=0;r<4;r++){
        int row = bm + wm*64 + i*16 + q*4 + r;
        int col = bn + wn*(BN/2) + j*16 + n16;
        float v = acc[i][j][r];
        if (ACT==1) v = softplusf_(v);
        else if (ACT==2) v = sigmoidf_(v);
        else if (ACT==3) v *= sigmoidf_(gate[(size_t)row*N+col]);
        C[(size_t)row*N+col] = v;
      }
    }
  }
}

// split fp32 weight [K][N] -> transposed bf16 hi/lo [N][K] (out-coalesced)
__global__ void splitT(const float* __restrict__ W,
                       unsigned short* __restrict__ hT, unsigned short* __restrict__ lT,
                       int K, int N)
{
  int idx = blockIdx.x*256 + threadIdx.x;
  if (idx >= N*K) return;
  int nn = idx / K, k = idx - nn*K;
  float v = W[(size_t)k*N + nn];
  unsigned short h = bf16rn(v);
  hT[idx] = h;
  lT[idx] = bf16rn(v - bf16tof(h));
}

__global__ __launch_bounds__(128) void conv_ln_kernel(
  const float* __restrict__ k_raw, const float* __restrict__ v_raw,
  const float* __restrict__ conv_w, const float* __restrict__ conv_b,
  const float* __restrict__ kn_g, const float* __restrict__ kn_b,
  float* __restrict__ k_out, float* __restrict__ v_out)
{
  int s = blockIdx.x, b = blockIdx.y, which = blockIdx.z;
  int h = threadIdx.x;
  const float* src = (which==0) ? k_raw : v_raw;
  float acc = conv_b[h];
  #pragma unroll
  for (int j=0;j<4;j++){
    int ss = s-3+j;
    if (ss>=0) acc += conv_w[h*4+j]*src[((size_t)b*Sq+ss)*Hq + h];
  }
  if (which==0){
    __shared__ float red[4];
    float sv = acc, s2 = acc*acc;
    #pragma unroll
    for (int off=32; off>0; off>>=1){
      sv += __shfl_down(sv, off, 64);
      s2 += __shfl_down(s2, off, 64);
    }
    if ((h&63)==0){ red[(h>>6)*2]=sv; red[(h>>6)*2+1]=s2; }
    __syncthreads();
    float mean = (red[0]+red[2])*(1.f/128.f);
    float var  = (red[1]+red[3])*(1.f/128.f) - mean*mean;
    float y = (acc-mean)*rsqrtf(var+1e-5f)*kn_g[h]+kn_b[h];
    k_out[((size_t)b*Sq+s)*Hq + h] = y;
  } else {
    v_out[((size_t)b*Sq+s)*Hq + h] = acc;
  }
}

// MFMA scan: 1 block/batch, 512 thr (8 waves). State register-resident (fp32
// masters, bf16 hi/lo 3-MFMA). Prefetch: kc/alpha/eta for t+1 loaded during t;
// v/delta for t issued at chunk start (consumed after GEMM2).
__global__ __launch_bounds__(512, 2) void scan_mfma(
  const float* __restrict__ k_ln, const float* __restrict__ v_c,
  const float* __restrict__ eta, const float* __restrict__ delta,
  const float* __restrict__ alpha,
  const float* __restrict__ mW1, const float* __restrict__ mb1,
  const float* __restrict__ mW2, const float* __restrict__ mb2,
  float* __restrict__ combined)
{
  __shared__ __align__(16) unsigned short kc_hi[Cq*Hq];
  __shared__ __align__(16) unsigned short kc_lo[Cq*Hq];
  __shared__ __align__(16) unsigned short act_hi[Cq*Mq];
  __shared__ __align__(16) unsigned short act_lo[Cq*Mq];
  __shared__ float Sam[Mq], Sus[Hq], Sb1[Mq], Sb2[Hq];
  __shared__ float Sen[Cq];
  __shared__ float pen[8][Cq];
  __shared__ float pb1u[8][Mq];
  __shared__ float Sabp[2], Sebp[2];

  const int b = blockIdx.x;
  const int tid = threadIdx.x;
  const int wv = tid >> 6;
  const int lane = tid & 63;
  const int n = lane & 15;
  const int q = lane >> 4;

  float w1m[2][4][8];  // W1[m=(2wv+t)*16+n][h=ks*32+q*8+j]
  float w2m[8][8];     // W2[h=wv*16+n][m=ks2*32+q*8+j]
  #pragma unroll
  for (int tt=0;tt<2;tt++){
    int m = (2*wv+tt)*16 + n;
    #pragma unroll
    for (int ks=0;ks<4;ks++){
      const float* p = mW1 + (size_t)m*Hq + ks*32 + q*8;
      #pragma unroll
      for (int j=0;j<8;j++) w1m[tt][ks][j] = p[j];
    }
  }
  {
    int h = wv*16 + n;
    #pragma unroll
    for (int ks2=0;ks2<8;ks2++){
      const float* p = mW2 + (size_t)h*Mq + ks2*32 + q*8;
      #pragma unroll
      for (int j=0;j<8;j++) w2m[ks2][j] = p[j];
    }
  }
  if (tid < Mq) Sb1[tid] = mb1[tid];
  if (tid < Hq) Sb2[tid] = mb2[tid];

  // ---- prefetch chunk 0 ----
  float4 kcp[4];
  float abv=0.f, ebv=0.f;
  {
    const float* kcg = k_ln + ((size_t)b*Sq)*Hq;
    #pragma unroll
    for (int r4=0;r4<4;r4++){
      int idx4 = tid + 512*r4;
      int c = idx4>>5, h0 = (idx4&31)<<2;
      kcp[r4] = *(const float4*)(kcg + (size_t)c*Hq + h0);
    }
    if (tid < 128){
      size_t last = ((size_t)b*Sq + 63)*Hq + tid;
      abv = alpha[last]; ebv = eta[last];
    }
  }

  for (int t=0; t<NCHUNK; ++t){
    __syncthreads();   // LDS reuse guard across chunks
    const size_t base = ((size_t)b*Sq + (size_t)t*Cq)*Hq;
    const float ab_c = abv, eb_c = ebv;

    // issue v/delta loads for THIS chunk (consumed after GEMM2)
    float vp[16], dp[16];
    {
      const int h = wv*16 + n;
      #pragma unroll
      for (int ct=0;ct<4;ct++){
        #pragma unroll
        for (int r=0;r<4;r++){
          int c = ct*16 + q*4 + r;
          vp[ct*4+r] = v_c[base + (size_t)c*Hq + h];
          dp[ct*4+r] = delta[base + (size_t)c*Hq + h];
        }
      }
    }
    // P0: kc regs -> LDS bf16 hi/lo (XOR-swizzled)
    #pragma unroll
    for (int r4=0;r4<4;r4++){
      int idx4 = tid + 512*r4;
      int c  = idx4 >> 5;
      int h0 = (idx4 & 31) << 2;
      float4 v = kcp[r4];
      int pg  = (h0>>3) ^ (c & 15);
      int off = c*Hq + (pg<<3) + (h0&7);
      unsigned short h0s=bf16rn(v.x), h1s=bf16rn(v.y), h2s=bf16rn(v.z), h3s=bf16rn(v.w);
      unsigned short l0s=bf16rn(v.x-bf16tof(h0s)), l1s=bf16rn(v.y-bf16tof(h1s));
      unsigned short l2s=bf16rn(v.z-bf16tof(h2s)), l3s=bf16rn(v.w-bf16tof(h3s));
      *(unsigned*)&kc_hi[off]   = (unsigned)h0s | ((unsigned)h1s<<16);
      *(unsigned*)&kc_hi[off+2] = (unsigned)h2s | ((unsigned)h3s<<16);
      *(unsigned*)&kc_lo[off]   = (unsigned)l0s | ((unsigned)l1s<<16);
      *(unsigned*)&kc_lo[off+2] = (unsigned)l2s | ((unsigned)l3s<<16);
    }
    // aw/ew partials from prefetched regs (waves 0,1 hold h=tid)
    if (wv < 2){
      float a2 = ab_c, e2 = eb_c;
      #pragma unroll
      for (int mk=1;mk<64;mk<<=1){ a2 += __shfl_xor(a2,mk,64); e2 += __shfl_xor(e2,mk,64); }
      if (lane==0){ Sabp[wv] = a2; Sebp[wv] = e2; }
    }
    __syncthreads();

    // prefetch NEXT chunk (hidden under GEMMs)
    {
      int tn = (t+1 < NCHUNK) ? t+1 : t;
      const float* kcg = k_ln + ((size_t)b*Sq + (size_t)tn*Cq)*Hq;
      #pragma unroll
      for (int r4=0;r4<4;r4++){
        int idx4 = tid + 512*r4;
        int c = idx4>>5, h0 = (idx4&31)<<2;
        kcp[r4] = *(const float4*)(kcg + (size_t)c*Hq + h0);
      }
      if (tid < 128){
        size_t last = ((size_t)b*Sq + (size_t)tn*Cq + 63)*Hq + tid;
        abv = alpha[last]; ebv = eta[last];
      }
    }

    // ---- GEMM1: inter = kc @ W1^T ----
    f32x4 acc[2][4];
    #pragma unroll
    for (int tt=0;tt<2;tt++){
      #pragma unroll
      for (int ct=0;ct<4;ct++){ f32x4 z = {0.f,0.f,0.f,0.f}; acc[tt][ct]=z; }
    }
    #pragma unroll
    for (int ks=0;ks<4;ks++){
      short8 ah[4], al[4];
      #pragma unroll
      for (int ct=0;ct<4;ct++){
        int c = ct*16 + n;
        int pg = (ks*4 + q) ^ n;
        int off = c*Hq + (pg<<3);
        ah[ct] = *(const short8*)&kc_hi[off];
        al[ct] = *(const short8*)&kc_lo[off];
      }
      #pragma unroll
      for (int tt=0;tt<2;tt++){
        short8 bh, bl;
        #pragma unroll
        for (int j=0;j<8;j++){
          float x = w1m[tt][ks][j];
          unsigned short hs = bf16rn(x);
          bh[j] = (short)hs;
          bl[j] = (short)bf16rn(x - bf16tof(hs));
        }
        #pragma unroll
        for (int ct=0;ct<4;ct++)
          acc[tt][ct] = __builtin_amdgcn_mfma_f32_16x16x32_bf16(ah[ct], bh, acc[tt][ct], 0,0,0);
        #pragma unroll
        for (int ct=0;ct<4;ct++)
          acc[tt][ct] = __builtin_amdgcn_mfma_f32_16x16x32_bf16(al[ct], bh, acc[tt][ct], 0,0,0);
        #pragma unroll
        for (int ct=0;ct<4;ct++)
          acc[tt][ct] = __builtin_amdgcn_mfma_f32_16x16x32_bf16(ah[ct], bl, acc[tt][ct], 0,0,0);
      }
    }
    // gelu -> act LDS + am
    #pragma unroll
    for (int tt=0;tt<2;tt++){
      int m = (2*wv+tt)*16 + n;
      float b1v = Sb1[m];
      float amsum = 0.f;
      #pragma unroll
      for (int ct=0;ct<4;ct++){
        #pragma unroll
        for (int r=0;r<4;r++){
          float xg = acc[tt][ct][r] + b1v;
          float g = gelu_fast(xg);
          amsum += g;
          int c = ct*16 + q*4 + r;
          int pg = (m>>3) ^ (c & 15);
          int off = c*Mq + (pg<<3) + (m&7);
          unsigned short hs = bf16rn(g);
          act_hi[off] = hs;
          act_lo[off] = bf16rn(g - bf16tof(hs));
        }
      }
      amsum += __shfl_xor(amsum, 16, 64);
      amsum += __shfl_xor(amsum, 32, 64);
      if (q==0) Sam[m] = amsum*(1.f/64.f);
    }
    __syncthreads();

    // ---- GEMM2: out = act @ W2^T ----
    f32x4 acc2[4];
    #pragma unroll
    for (int ct=0;ct<4;ct++){ f32x4 z = {0.f,0.f,0.f,0.f}; acc2[ct]=z; }
    #pragma unroll
    for (int ks2=0;ks2<8;ks2++){
      short8 ah[4], al[4];
      #pragma unroll
      for (int ct=0;ct<4;ct++){
        int c = ct*16 + n;
        int pg = (ks2*4 + q) ^ n;
        int off = c*Mq + (pg<<3);
        ah[ct] = *(const short8*)&act_hi[off];
        al[ct] = *(const short8*)&act_lo[off];
      }
      short8 bh, bl;
      #pragma unroll
      for (int j=0;j<8;j++){
        float x = w2m[ks2][j];
        unsigned short hs = bf16rn(x);
        bh[j] = (short)hs;
        bl[j] = (short)bf16rn(x - bf16tof(hs));
      }
      #pragma unroll
      for (int ct=0;ct<4;ct++)
        acc2[ct] = __builtin_amdgcn_mfma_f32_16x16x32_bf16(ah[ct], bh, acc2[ct], 0,0,0);
      #pragma unroll
      for (int ct=0;ct<4;ct++)
        acc2[ct] = __builtin_amdgcn_mfma_f32_16x16x32_bf16(al[ct], bh, acc2[ct], 0,0,0);
      #pragma unroll
      for (int ct=0;ct<4;ct++)
        acc2[ct] = __builtin_amdgcn_mfma_f32_16x16x32_bf16(ah[ct], bl, acc2[ct], 0,0,0);
    }
    // out, combined, err, en partials
    float err[4][4];
    {
      int h = wv*16 + n;
      float b2v = Sb2[h];
      float* cb = combined + base;
      #pragma unroll
      for (int ct=0;ct<4;ct++){
        #pragma unroll
        for (int r=0;r<4;r++){
          int c = ct*16 + q*4 + r;
          float o = acc2[ct][r] + b2v;
          cb[(size_t)c*Hq + h] = o;
          err[ct][r] = o - vp[ct*4+r];
        }
      }
      #pragma unroll
      for (int ct=0;ct<4;ct++){
        #pragma unroll
        for (int r=0;r<4;r++){
          float s = err[ct][r]*err[ct][r];
          s += __shfl_xor(s,1,64); s += __shfl_xor(s,2,64);
          s += __shfl_xor(s,4,64); s += __shfl_xor(s,8,64);
          if (n==0) pen[wv][ct*16+q*4+r] = s;
        }
      }
    }
    __syncthreads();
    if (tid < Cq){
      float s = 0.f;
      #pragma unroll
      for (int w2=0;w2<8;w2++) s += pen[w2][tid];
      Sen[tid] = sqrtf(s);
    }
    __syncthreads();
    // grad + us
    {
      float uss = 0.f;
      #pragma unroll
      for (int ct=0;ct<4;ct++){
        #pragma unroll
        for (int r=0;r<4;r++){
          int c = ct*16 + q*4 + r;
          float en = Sen[c];
          float dv = dp[ct*4+r];
          float e = err[ct][r];
          float g = (en > dv) ? dv*e/(en+1e-9f) : e;
          err[ct][r] = g;
          uss += g;
        }
      }
      uss += __shfl_xor(uss,16,64);
      uss += __shfl_xor(uss,32,64);
      if (q==0) Sus[wv*16+n] = uss*(1.f/64.f);
    }
    __syncthreads();
    // state updates (registers) + b1u partials + b2
    {
      float aw = (Sabp[0]+Sabp[1])*(1.f/128.f);
      float ew = (Sebp[0]+Sebp[1])*(1.f/128.f);
      #pragma unroll
      for (int tt=0;tt<2;tt++){
        int m = (2*wv+tt)*16 + n;
        float eam = ew*Sam[m];
        #pragma unroll
        for (int ks=0;ks<4;ks++){
          #pragma unroll
          for (int j=0;j<8;j++){
            int h = ks*32 + q*8 + j;
            w1m[tt][ks][j] = aw*w1m[tt][ks][j] - eam*Sus[h];
          }
        }
      }
      int h = wv*16 + n;
      float ush = Sus[h];
      float eus = ew*ush;
      #pragma unroll
      for (int ks2=0;ks2<8;ks2++){
        #pragma unroll
        for (int j=0;j<8;j++){
          int m = ks2*32 + q*8 + j;
          w2m[ks2][j] = aw*w2m[ks2][j] - eus*Sam[m];
        }
      }
      #pragma unroll
      for (int ks2=0;ks2<8;ks2++){
        float s8[8];
        #pragma unroll
        for (int j=0;j<8;j++) s8[j] = ush*w2m[ks2][j];
        #pragma unroll
        for (int mk=1;mk<16;mk<<=1){
          #pragma unroll
          for (int j=0;j<8;j++) s8[j] += __shfl_xor(s8[j], mk, 64);
        }
        if (n==0){
          #pragma unroll
          for (int j=0;j<8;j++) pb1u[wv][ks2*32 + q*8 + j] = s8[j];
        }
      }
      if (tid < Hq) Sb2[tid] = ab_c*Sb2[tid] - eb_c*Sus[tid];
    }
    __syncthreads();
    if (tid < Mq){
      float aw = (Sabp[0]+Sabp[1])*(1.f/128.f);
      float ew = (Sebp[0]+Sebp[1])*(1.f/128.f);
      float s=0.f;
      #pragma unroll
      for (int w2=0;w2<8;w2++) s += pb1u[w2][tid];
      Sb1[tid] = aw*Sb1[tid] - ew*s;
    }
  }
}

extern "C" void kernel_launch(void* const* d_in, const int* in_sizes, int n_in,
                              void* d_out, int out_size, void* d_ws, size_t ws_size,
                              hipStream_t stream)
{
  const float* x    = (const float*)d_in[0];
  // d_in[1]=Wq, d_in[14],[15]=qn_g/qn_b: dead (q path unused by output).
  const float* Wk   = (const float*)d_in[2];
  const float* Wv   = (const float*)d_in[3];
  const float* Wo   = (const float*)d_in[4];
  const float* Wg   = (const float*)d_in[5];
  const float* We1  = (const float*)d_in[6];
  const float* We2  = (const float*)d_in[7];
  const float* Wd1  = (const float*)d_in[8];
  const float* Wd2  = (const float*)d_in[9];
  const float* Wa1  = (const float*)d_in[10];
  const float* Wa2  = (const float*)d_in[11];
  const float* conv_w = (const float*)d_in[12];
  const float* conv_b = (const float*)d_in[13];
  const float* kn_g = (const float*)d_in[16];
  const float* kn_b = (const float*)d_in[17];
  const float* mW1  = (const float*)d_in[18];
  const float* mb1  = (const float*)d_in[19];
  const float* mW2  = (const float*)d_in[20];
  const float* mb2  = (const float*)d_in[21];
  float* out = (float*)d_out;

  float* ws = (float*)d_ws;
  size_t o = 0;
  float* k_raw = ws + o; o += (size_t)BSq*Hq;
  float* v_raw = ws + o; o += (size_t)BSq*Hq;
  float* te    = ws + o; o += (size_t)BSq*Rq;
  float* td    = ws + o; o += (size_t)BSq*Rq;
  float* ta    = ws + o; o += (size_t)BSq*Rq;
  float* glog  = ws + o; o += (size_t)BSq*Dq;
  float* etab  = ws + o; o += (size_t)BSq*Hq;
  float* deltab= ws + o; o += (size_t)BSq*Hq;
  float* alphab= ws + o; o += (size_t)BSq*Hq;
  float* k_ln  = ws + o; o += (size_t)BSq*Hq;
  float* v_c   = ws + o; o += (size_t)BSq*Hq;
  float* comb  = ws + o; o += (size_t)BSq*Hq;
  // pre-split transposed bf16 weights
  unsigned short* us = (unsigned short*)(ws + o);
  size_t u = 0;
  unsigned short *WkTh = us+u; u += (size_t)Hq*Dq;  unsigned short *WkTl = us+u; u += (size_t)Hq*Dq;
  unsigned short *WvTh = us+u; u += (size_t)Hq*Dq;  unsigned short *WvTl = us+u; u += (size_t)Hq*Dq;
  unsigned short *We1Th= us+u; u += (size_t)Rq*Dq;  unsigned short *We1Tl= us+u; u += (size_t)Rq*Dq;
  unsigned short *Wd1Th= us+u; u += (size_t)Rq*Dq;  unsigned short *Wd1Tl= us+u; u += (size_t)Rq*Dq;
  unsigned short *Wa1Th= us+u; u += (size_t)Rq*Dq;  unsigned short *Wa1Tl= us+u; u += (size_t)Rq*Dq;
  unsigned short *WgTh = us+u; u += (size_t)Dq*Dq;  unsigned short *WgTl = us+u; u += (size_t)Dq*Dq;
  unsigned short *We2Th= us+u; u += (size_t)Hq*Rq;  unsigned short *We2Tl= us+u; u += (size_t)Hq*Rq;
  unsigned short *Wd2Th= us+u; u += (size_t)Hq*Rq;  unsigned short *Wd2Tl= us+u; u += (size_t)Hq*Rq;
  unsigned short *Wa2Th= us+u; u += (size_t)Hq*Rq;  unsigned short *Wa2Tl= us+u; u += (size_t)Hq*Rq;
  unsigned short *WoTh = us+u; u += (size_t)Dq*Hq;  unsigned short *WoTl = us+u; u += (size_t)Dq*Hq;

  // weight splits (K,N of original)
  splitT<<<(Hq*Dq+255)/256, 256, 0, stream>>>(Wk,  WkTh,  WkTl,  Dq, Hq);
  splitT<<<(Hq*Dq+255)/256, 256, 0, stream>>>(Wv,  WvTh,  WvTl,  Dq, Hq);
  splitT<<<(Rq*Dq+255)/256, 256, 0, stream>>>(We1, We1Th, We1Tl, Dq, Rq);
  splitT<<<(Rq*Dq+255)/256, 256, 0, stream>>>(Wd1, Wd1Th, Wd1Tl, Dq, Rq);
  splitT<<<(Rq*Dq+255)/256, 256, 0, stream>>>(Wa1, Wa1Th, Wa1Tl, Dq, Rq);
  splitT<<<(Dq*Dq+255)/256, 256, 0, stream>>>(Wg,  WgTh,  WgTl,  Dq, Dq);
  splitT<<<(Hq*Rq+255)/256, 256, 0, stream>>>(We2, We2Th, We2Tl, Rq, Hq);
  splitT<<<(Hq*Rq+255)/256, 256, 0, stream>>>(Wd2, Wd2Th, Wd2Tl, Rq, Hq);
  splitT<<<(Hq*Rq+255)/256, 256, 0, stream>>>(Wa2, Wa2Th, Wa2Tl, Rq, Hq);
  splitT<<<(Dq*Hq+255)/256, 256, 0, stream>>>(Wo,  WoTh,  WoTl,  Hq, Dq);

  dim3 blk(256);
  // stage-1 projections (A = x fp32, split in-kernel)
  gemm_bf3<128,0><<<dim3(1,   BSq/128), blk, 0, stream>>>(x, WkTh, WkTl, k_raw, nullptr, Hq, Dq);
  gemm_bf3<128,0><<<dim3(1,   BSq/128), blk, 0, stream>>>(x, WvTh, WvTl, v_raw, nullptr, Hq, Dq);
  gemm_bf3<64,0> <<<dim3(1,   BSq/128), blk, 0, stream>>>(x, We1Th, We1Tl, te, nullptr, Rq, Dq);
  gemm_bf3<64,0> <<<dim3(1,   BSq/128), blk, 0, stream>>>(x, Wd1Th, Wd1Tl, td, nullptr, Rq, Dq);
  gemm_bf3<64,0> <<<dim3(1,   BSq/128), blk, 0, stream>>>(x, Wa1Th, Wa1Tl, ta, nullptr, Rq, Dq);
  gemm_bf3<128,0><<<dim3(Dq/128, BSq/128), blk, 0, stream>>>(x, WgTh, WgTl, glog, nullptr, Dq, Dq);
  // stage-2 small GEMMs with activations
  gemm_bf3<128,1><<<dim3(1, BSq/128), blk, 0, stream>>>(te, We2Th, We2Tl, etab,   nullptr, Hq, Rq);
  gemm_bf3<128,1><<<dim3(1, BSq/128), blk, 0, stream>>>(td, Wd2Th, Wd2Tl, deltab, nullptr, Hq, Rq);
  gemm_bf3<128,2><<<dim3(1, BSq/128), blk, 0, stream>>>(ta, Wa2Th, Wa2Tl, alphab, nullptr, Hq, Rq);
  // conv + LN
  conv_ln_kernel<<<dim3(Sq, Bq, 2), dim3(128), 0, stream>>>(
      k_raw, v_raw, conv_w, conv_b, kn_g, kn_b, k_ln, v_c);
  // sequential scan
  scan_mfma<<<Bq, 512, 0, stream>>>(k_ln, v_c, etab, deltab, alphab,
                                    mW1, mb1, mW2, mb2, comb);
  // final: (comb @ Wo) * sigmoid(glog)
  gemm_bf3<128,3><<<dim3(Dq/128, BSq/128), blk, 0, stream>>>(comb, WoTh, WoTl, out, glog, Dq, Hq);
}

// Round 4
// 2226.786 us; speedup vs baseline: 3.3787x; 1.1552x over previous
//
#include <hip/hip_runtime.h>
#include <math.h>

#define Bq 4
#define Sq 4096
#define Dq 1024
#define Hq 128
#define Mq 256
#define Rq 64
#define Cq 64
#define NCHUNK 64
#define BSq (Bq*Sq)

typedef __attribute__((ext_vector_type(8))) short short8;
typedef __attribute__((ext_vector_type(4))) float f32x4;

__device__ __forceinline__ float softplusf_(float x){
  return fmaxf(x,0.f) + log1pf(expf(-fabsf(x)));
}
__device__ __forceinline__ float sigmoidf_(float x){
  return 1.f/(1.f+__expf(-x));
}
__device__ __forceinline__ unsigned short bf16rn(float x){
  unsigned u = __float_as_uint(x);
  u += 0x7fffu + ((u>>16)&1u);
  return (unsigned short)(u>>16);
}
__device__ __forceinline__ float bf16tof(unsigned short s){
  return __uint_as_float(((unsigned)s)<<16);
}
// branchless erf-gelu (A&S 7.1.26, |err|<=1.5e-7)
__device__ __forceinline__ float gelu_fast(float x){
  float z  = x*0.70710678118f;
  float az = fabsf(z);
  float t  = __builtin_amdgcn_rcpf(fmaf(0.3275911f, az, 1.f));
  float p  = fmaf(t, 1.061405429f, -1.453152027f);
  p = fmaf(t, p, 1.421413741f);
  p = fmaf(t, p, -0.284496736f);
  p = fmaf(t, p, 0.254829592f);
  p = p*t;
  float e  = __expf(-az*az);
  float er = copysignf(1.f - p*e, z);
  return 0.5f*x*(1.f + er);
}

// ---------------- bf16x3 MFMA GEMM (256 thr) ----------------
template<int BN, int ACT>
__global__ __launch_bounds__(256) void gemm_bf3(
    const float* __restrict__ Af,
    const unsigned short* __restrict__ BhT, const unsigned short* __restrict__ BlT,
    float* __restrict__ C, const float* __restrict__ gate, int N, int K)
{
  constexpr int BM = 128;
  constexpr int PK = 40;
  constexpr int TN = BN/32;
  __shared__ __align__(16) unsigned short As[2][BM*PK];
  __shared__ __align__(16) unsigned short Bs[2][BN*PK];
  const int tid = threadIdx.x;
  const int bm = blockIdx.y*BM, bn = blockIdx.x*BN;
  const int wv = tid>>6, lane = tid&63;
  const int n16 = lane&15, q = lane>>4;
  const int wm = wv>>1, wn = wv&1;

  f32x4 acc[4][TN];
  #pragma unroll
  for (int i=0;i<4;i++){
    #pragma unroll
    for (int j=0;j<TN;j++){ f32x4 z={0.f,0.f,0.f,0.f}; acc[i][j]=z; }
  }
  for (int k0=0;k0<K;k0+=32){
    #pragma unroll
    for (int c0=0;c0<BM*8;c0+=256){
      int c = c0 + tid;
      int row = c>>3, kg = (c&7)*4;
      float4 v = *(const float4*)&Af[(size_t)(bm+row)*K + k0+kg];
      unsigned short h0=bf16rn(v.x),h1=bf16rn(v.y),h2=bf16rn(v.z),h3=bf16rn(v.w);
      unsigned short l0=bf16rn(v.x-bf16tof(h0)),l1=bf16rn(v.y-bf16tof(h1));
      unsigned short l2=bf16rn(v.z-bf16tof(h2)),l3=bf16rn(v.w-bf16tof(h3));
      int off = row*PK+kg;
      *(unsigned*)&As[0][off]   = (unsigned)h0 | ((unsigned)h1<<16);
      *(unsigned*)&As[0][off+2] = (unsigned)h2 | ((unsigned)h3<<16);
      *(unsigned*)&As[1][off]   = (unsigned)l0 | ((unsigned)l1<<16);
      *(unsigned*)&As[1][off+2] = (unsigned)l2 | ((unsigned)l3<<16);
    }
    #pragma unroll
    for (int c0=0;c0<BN*4;c0+=256){
      int c = c0 + tid;
      int row = c>>2, kg = (c&3)*8;
      *(short8*)&Bs[0][row*PK+kg] = *(const short8*)&BhT[(size_t)(bn+row)*K + k0+kg];
      *(short8*)&Bs[1][row*PK+kg] = *(const short8*)&BlT[(size_t)(bn+row)*K + k0+kg];
    }
    __syncthreads();
    short8 a_h[4], a_l[4], b_h[TN], b_l[TN];
    #pragma unroll
    for (int i=0;i<4;i++){
      int r = wm*64 + i*16 + n16;
      a_h[i] = *(const short8*)&As[0][r*PK + q*8];
      a_l[i] = *(const short8*)&As[1][r*PK + q*8];
    }
    #pragma unroll
    for (int j=0;j<TN;j++){
      int r = wn*(BN/2) + j*16 + n16;
      b_h[j] = *(const short8*)&Bs[0][r*PK + q*8];
      b_l[j] = *(const short8*)&Bs[1][r*PK + q*8];
    }
    #pragma unroll
    for (int i=0;i<4;i++){
      #pragma unroll
      for (int j=0;j<TN;j++){
        acc[i][j] = __builtin_amdgcn_mfma_f32_16x16x32_bf16(a_h[i], b_h[j], acc[i][j], 0,0,0);
        acc[i][j] = __builtin_amdgcn_mfma_f32_16x16x32_bf16(a_l[i], b_h[j], acc[i][j], 0,0,0);
        acc[i][j] = __builtin_amdgcn_mfma_f32_16x16x32_bf16(a_h[i], b_l[j], acc[i][j], 0,0,0);
      }
    }
    __syncthreads();
  }
  #pragma unroll
  for (int i=0;i<4;i++){
    #pragma unroll
    for (int j=0;j<TN;j++){
      #pragma unroll
      for (int r=0;r<4;r++){
        int row = bm + wm*64 + i*16 + q*4 + r;
        int col = bn + wn*(BN/2) + j*16 + n16;
        float v = acc[i][j][r];
        if (ACT==1) v = softplusf_(v);
        else if (ACT==2) v = sigmoidf_(v);
        else if (ACT==3) v *= sigmoidf_(gate[(size_t)row*N+col]);
        C[(size_t)row*N+col] = v;
      }
    }
  }
}

__global__ void splitT(const float* __restrict__ W,
                       unsigned short* __restrict__ hT, unsigned short* __restrict__ lT,
                       int K, int N)
{
  int idx = blockIdx.x*256 + threadIdx.x;
  if (idx >= N*K) return;
  int nn = idx / K, k = idx - nn*K;
  float v = W[(size_t)k*N + nn];
  unsigned short h = bf16rn(v);
  hT[idx] = h;
  lT[idx] = bf16rn(v - bf16tof(h));
}

__global__ __launch_bounds__(128) void conv_ln_kernel(
  const float* __restrict__ k_raw, const float* __restrict__ v_raw,
  const float* __restrict__ conv_w, const float* __restrict__ conv_b,
  const float* __restrict__ kn_g, const float* __restrict__ kn_b,
  float* __restrict__ k_out, float* __restrict__ v_out)
{
  int s = blockIdx.x, b = blockIdx.y, which = blockIdx.z;
  int h = threadIdx.x;
  const float* src = (which==0) ? k_raw : v_raw;
  float acc = conv_b[h];
  #pragma unroll
  for (int j=0;j<4;j++){
    int ss = s-3+j;
    if (ss>=0) acc += conv_w[h*4+j]*src[((size_t)b*Sq+ss)*Hq + h];
  }
  if (which==0){
    __shared__ float red[4];
    float sv = acc, s2 = acc*acc;
    #pragma unroll
    for (int off=32; off>0; off>>=1){
      sv += __shfl_down(sv, off, 64);
      s2 += __shfl_down(s2, off, 64);
    }
    if ((h&63)==0){ red[(h>>6)*2]=sv; red[(h>>6)*2+1]=s2; }
    __syncthreads();
    float mean = (red[0]+red[2])*(1.f/128.f);
    float var  = (red[1]+red[3])*(1.f/128.f) - mean*mean;
    float y = (acc-mean)*rsqrtf(var+1e-5f)*kn_g[h]+kn_b[h];
    k_out[((size_t)b*Sq+s)*Hq + h] = y;
  } else {
    v_out[((size_t)b*Sq+s)*Hq + h] = acc;
  }
}

// ---- LDS overlay offsets (bytes) for the fused kernel's scan branch ----
#define OFF_KCH   0            // 64*128*2        = 16384
#define OFF_KCL   16384        // 16384
#define OFF_ACTH  32768        // 64*256*2        = 32768
#define OFF_SV    65536        // 64*132*4        = 33792
#define OFF_SD    99328        // 33792
#define OFF_SAM   133120       // 256*4
#define OFF_SUS   134144       // 128*4
#define OFF_SEN   134656       // 64*4
#define OFF_PEN   134912       // 8*64*4
#define OFF_SAB   136960       // 128*4
#define OFF_SEB   137472       // 128*4
#define OFF_SABP  137984       // 2*4
#define OFF_SEBP  137992       // 2*4
#define LDS_TOTAL 138016

// Fused kernel: blocks 0..3 = sequential scan (1 per batch);
// blocks 4.. = Wg GEMM tiles (x @ Wg, 128x128, bf16x3), co-scheduled on idle CUs.
__global__ __launch_bounds__(512, 2) void fused_scan_wg(
  const float* __restrict__ k_ln, const float* __restrict__ v_c,
  const float* __restrict__ eta, const float* __restrict__ delta,
  const float* __restrict__ alpha,
  const float* __restrict__ mW1, const float* __restrict__ mb1,
  const float* __restrict__ mW2, const float* __restrict__ mb2,
  float* __restrict__ combined,
  const float* __restrict__ x,
  const unsigned short* __restrict__ WgTh, const unsigned short* __restrict__ WgTl,
  float* __restrict__ glog)
{
  __shared__ __align__(16) char smem[LDS_TOTAL];
  const int blk = blockIdx.x;
  const int tid = threadIdx.x;
  const int wv = tid >> 6;
  const int lane = tid & 63;
  const int n = lane & 15;
  const int q = lane >> 4;

  if (blk >= 4){
    // ================= Wg GEMM branch (512 thr, 128x128 tile) =================
    unsigned short* As_h = (unsigned short*)smem;          // 128*40
    unsigned short* As_l = As_h + 128*40;
    unsigned short* Bs_h = As_l + 128*40;
    unsigned short* Bs_l = Bs_h + 128*40;
    const int g = blk - 4;
    const int bm = (g>>3)*128, bn = (g&7)*128;
    const int wm = wv&3, wn = wv>>2;
    f32x4 acc[2][4];
    #pragma unroll
    for (int i=0;i<2;i++){
      #pragma unroll
      for (int j=0;j<4;j++){ f32x4 z={0.f,0.f,0.f,0.f}; acc[i][j]=z; }
    }
    for (int k0=0;k0<Dq;k0+=32){
      #pragma unroll
      for (int r=0;r<2;r++){
        int idx = tid + 512*r;
        int row = idx>>3, kg = (idx&7)*4;
        float4 v = *(const float4*)&x[(size_t)(bm+row)*Dq + k0+kg];
        unsigned short h0=bf16rn(v.x),h1=bf16rn(v.y),h2=bf16rn(v.z),h3=bf16rn(v.w);
        unsigned short l0=bf16rn(v.x-bf16tof(h0)),l1=bf16rn(v.y-bf16tof(h1));
        unsigned short l2=bf16rn(v.z-bf16tof(h2)),l3=bf16rn(v.w-bf16tof(h3));
        int off = row*40+kg;
        *(unsigned*)&As_h[off]   = (unsigned)h0 | ((unsigned)h1<<16);
        *(unsigned*)&As_h[off+2] = (unsigned)h2 | ((unsigned)h3<<16);
        *(unsigned*)&As_l[off]   = (unsigned)l0 | ((unsigned)l1<<16);
        *(unsigned*)&As_l[off+2] = (unsigned)l2 | ((unsigned)l3<<16);
      }
      {
        int row = tid>>2, kg = (tid&3)*8;
        *(short8*)&Bs_h[row*40+kg] = *(const short8*)&WgTh[(size_t)(bn+row)*Dq + k0+kg];
        *(short8*)&Bs_l[row*40+kg] = *(const short8*)&WgTl[(size_t)(bn+row)*Dq + k0+kg];
      }
      __syncthreads();
      short8 a_h[2], a_l[2], b_h[4], b_l[4];
      #pragma unroll
      for (int i=0;i<2;i++){
        int r = wm*32 + i*16 + n;
        a_h[i] = *(const short8*)&As_h[r*40 + q*8];
        a_l[i] = *(const short8*)&As_l[r*40 + q*8];
      }
      #pragma unroll
      for (int j=0;j<4;j++){
        int r = wn*64 + j*16 + n;
        b_h[j] = *(const short8*)&Bs_h[r*40 + q*8];
        b_l[j] = *(const short8*)&Bs_l[r*40 + q*8];
      }
      #pragma unroll
      for (int i=0;i<2;i++){
        #pragma unroll
        for (int j=0;j<4;j++){
          acc[i][j] = __builtin_amdgcn_mfma_f32_16x16x32_bf16(a_h[i], b_h[j], acc[i][j], 0,0,0);
          acc[i][j] = __builtin_amdgcn_mfma_f32_16x16x32_bf16(a_l[i], b_h[j], acc[i][j], 0,0,0);
          acc[i][j] = __builtin_amdgcn_mfma_f32_16x16x32_bf16(a_h[i], b_l[j], acc[i][j], 0,0,0);
        }
      }
      __syncthreads();
    }
    #pragma unroll
    for (int i=0;i<2;i++){
      #pragma unroll
      for (int j=0;j<4;j++){
        #pragma unroll
        for (int r=0;r<4;r++){
          int row = bm + wm*32 + i*16 + q*4 + r;
          int col = bn + wn*64 + j*16 + n;
          glog[(size_t)row*Dq+col] = acc[i][j][r];
        }
      }
    }
    return;
  }

  // ================= scan branch =================
  unsigned short* kc_hi  = (unsigned short*)(smem + OFF_KCH);
  unsigned short* kc_lo  = (unsigned short*)(smem + OFF_KCL);
  unsigned short* act_hi = (unsigned short*)(smem + OFF_ACTH);
  float* Sv  = (float*)(smem + OFF_SV);    // [c][132]
  float* Sd  = (float*)(smem + OFF_SD);    // [c][132]
  float* Sam = (float*)(smem + OFF_SAM);
  float* Sus = (float*)(smem + OFF_SUS);
  float* Sen = (float*)(smem + OFF_SEN);
  float* pen = (float*)(smem + OFF_PEN);   // [8][64]
  float* Sab = (float*)(smem + OFF_SAB);
  float* Seb = (float*)(smem + OFF_SEB);
  float* Sabp = (float*)(smem + OFF_SABP);
  float* Sebp = (float*)(smem + OFF_SEBP);

  const int b = blk;
  // state masters (registers): W1, W2 (GEMM2 layout), W2T (W1-layout copy for b1u)
  float w1m[2][4][8];   // W1[m=(2wv+tt)*16+n][h=ks*32+q*8+j]
  float w2m[8][8];      // W2[h=wv*16+n][m=ks2*32+q*8+j]
  float w2t[2][4][8];   // W2[h=ks*32+q*8+j][m=(2wv+tt)*16+n]
  float b1reg[2], b2reg;
  #pragma unroll
  for (int tt=0;tt<2;tt++){
    int m = (2*wv+tt)*16 + n;
    #pragma unroll
    for (int ks=0;ks<4;ks++){
      const float* p = mW1 + (size_t)m*Hq + ks*32 + q*8;
      #pragma unroll
      for (int j=0;j<8;j++) w1m[tt][ks][j] = p[j];
      #pragma unroll
      for (int j=0;j<8;j++) w2t[tt][ks][j] = mW2[(size_t)(ks*32+q*8+j)*Mq + m];
    }
    b1reg[tt] = mb1[m];
  }
  {
    int h = wv*16 + n;
    #pragma unroll
    for (int ks2=0;ks2<8;ks2++){
      const float* p = mW2 + (size_t)h*Mq + ks2*32 + q*8;
      #pragma unroll
      for (int j=0;j<8;j++) w2m[ks2][j] = p[j];
    }
    b2reg = mb2[h];
  }

  for (int t=0; t<NCHUNK; ++t){
    __syncthreads();   // LDS reuse guard
    const size_t base = ((size_t)b*Sq + (size_t)t*Cq)*Hq;
    // ---- P0: load chunk data ----
    float4 kcl[4], vl[4], dl[4];
    #pragma unroll
    for (int r4=0;r4<4;r4++){
      int i4 = tid + 512*r4;
      kcl[r4] = *(const float4*)(k_ln + base + (size_t)i4*4);
      vl[r4]  = *(const float4*)(v_c  + base + (size_t)i4*4);
      dl[r4]  = *(const float4*)(delta+ base + (size_t)i4*4);
    }
    float ab_=0.f, eb_=0.f;
    if (tid < 128){
      ab_ = alpha[base + 63*Hq + tid];
      eb_ = eta[base + 63*Hq + tid];
      Sab[tid] = ab_; Seb[tid] = eb_;
    }
    #pragma unroll
    for (int r4=0;r4<4;r4++){
      int i4 = tid + 512*r4;
      int c = i4>>5, h0 = (i4&31)<<2;
      float4 v = kcl[r4];
      int pg  = (h0>>3) ^ (c & 15);
      int off = c*Hq + (pg<<3) + (h0&7);
      unsigned short h0s=bf16rn(v.x), h1s=bf16rn(v.y), h2s=bf16rn(v.z), h3s=bf16rn(v.w);
      unsigned short l0s=bf16rn(v.x-bf16tof(h0s)), l1s=bf16rn(v.y-bf16tof(h1s));
      unsigned short l2s=bf16rn(v.z-bf16tof(h2s)), l3s=bf16rn(v.w-bf16tof(h3s));
      *(unsigned*)&kc_hi[off]   = (unsigned)h0s | ((unsigned)h1s<<16);
      *(unsigned*)&kc_hi[off+2] = (unsigned)h2s | ((unsigned)h3s<<16);
      *(unsigned*)&kc_lo[off]   = (unsigned)l0s | ((unsigned)l1s<<16);
      *(unsigned*)&kc_lo[off+2] = (unsigned)l2s | ((unsigned)l3s<<16);
      *(float4*)(Sv + c*132 + h0) = vl[r4];
      *(float4*)(Sd + c*132 + h0) = dl[r4];
    }
    if (wv < 2){
      float a2 = ab_, e2 = eb_;
      #pragma unroll
      for (int mk=1;mk<64;mk<<=1){ a2 += __shfl_xor(a2,mk,64); e2 += __shfl_xor(e2,mk,64); }
      if (lane==0){ Sabp[wv] = a2; Sebp[wv] = e2; }
    }
    __syncthreads();

    // ---- GEMM1: inter = kc @ W1^T (kc hi/lo, W1 hi/lo: 3-MFMA) ----
    f32x4 acc1[2][4];
    #pragma unroll
    for (int tt=0;tt<2;tt++){
      #pragma unroll
      for (int ct=0;ct<4;ct++){ f32x4 z={0.f,0.f,0.f,0.f}; acc1[tt][ct]=z; }
    }
    #pragma unroll
    for (int ks=0;ks<4;ks++){
      short8 bh[2], bl[2];
      #pragma unroll
      for (int tt=0;tt<2;tt++){
        #pragma unroll
        for (int j=0;j<8;j++){
          float xv = w1m[tt][ks][j];
          unsigned short hs = bf16rn(xv);
          bh[tt][j] = (short)hs;
          bl[tt][j] = (short)bf16rn(xv - bf16tof(hs));
        }
      }
      #pragma unroll
      for (int ct=0;ct<4;ct++){
        int c = ct*16 + n;
        int off = c*Hq + ((((ks*4+q)^n))<<3);
        short8 ah = *(const short8*)&kc_hi[off];
        short8 al = *(const short8*)&kc_lo[off];
        #pragma unroll
        for (int tt=0;tt<2;tt++){
          acc1[tt][ct] = __builtin_amdgcn_mfma_f32_16x16x32_bf16(ah, bh[tt], acc1[tt][ct], 0,0,0);
          acc1[tt][ct] = __builtin_amdgcn_mfma_f32_16x16x32_bf16(al, bh[tt], acc1[tt][ct], 0,0,0);
          acc1[tt][ct] = __builtin_amdgcn_mfma_f32_16x16x32_bf16(ah, bl[tt], acc1[tt][ct], 0,0,0);
        }
      }
    }
    // gelu -> act_hi + am
    #pragma unroll
    for (int tt=0;tt<2;tt++){
      int m = (2*wv+tt)*16 + n;
      float b1v = b1reg[tt];
      float amsum = 0.f;
      #pragma unroll
      for (int ct=0;ct<4;ct++){
        #pragma unroll
        for (int r=0;r<4;r++){
          float g = gelu_fast(acc1[tt][ct][r] + b1v);
          amsum += g;
          int c = ct*16 + q*4 + r;
          int pg = (m>>3) ^ (c & 15);
          act_hi[c*Mq + (pg<<3) + (m&7)] = bf16rn(g);
        }
      }
      amsum += __shfl_xor(amsum, 16, 64);
      amsum += __shfl_xor(amsum, 32, 64);
      if (q==0) Sam[m] = amsum*(1.f/64.f);
    }
    __syncthreads();

    // ---- GEMM2: out = act @ W2^T (act hi only, W2 hi/lo: 2-MFMA) ----
    f32x4 acc2[4];
    #pragma unroll
    for (int ct=0;ct<4;ct++){ f32x4 z={0.f,0.f,0.f,0.f}; acc2[ct]=z; }
    #pragma unroll
    for (int ks2=0;ks2<8;ks2++){
      short8 bh, bl;
      #pragma unroll
      for (int j=0;j<8;j++){
        float xv = w2m[ks2][j];
        unsigned short hs = bf16rn(xv);
        bh[j] = (short)hs;
        bl[j] = (short)bf16rn(xv - bf16tof(hs));
      }
      #pragma unroll
      for (int ct=0;ct<4;ct++){
        int c = ct*16 + n;
        int off = c*Mq + ((((ks2*4+q)^n))<<3);
        short8 ah = *(const short8*)&act_hi[off];
        acc2[ct] = __builtin_amdgcn_mfma_f32_16x16x32_bf16(ah, bh, acc2[ct], 0,0,0);
        acc2[ct] = __builtin_amdgcn_mfma_f32_16x16x32_bf16(ah, bl, acc2[ct], 0,0,0);
      }
    }
    // out, combined, err, en partials
    const int h = wv*16 + n;
    float err[4][4];
    {
      float* cb = combined + base;
      #pragma unroll
      for (int ct=0;ct<4;ct++){
        #pragma unroll
        for (int r=0;r<4;r++){
          int c = ct*16 + q*4 + r;
          float o = acc2[ct][r] + b2reg;
          cb[(size_t)c*Hq + h] = o;
          err[ct][r] = o - Sv[c*132 + h];
        }
      }
      #pragma unroll
      for (int ct=0;ct<4;ct++){
        #pragma unroll
        for (int r=0;r<4;r++){
          float s = err[ct][r]*err[ct][r];
          s += __shfl_xor(s,1,64); s += __shfl_xor(s,2,64);
          s += __shfl_xor(s,4,64); s += __shfl_xor(s,8,64);
          if (n==0) pen[wv*64 + ct*16+q*4+r] = s;
        }
      }
    }
    __syncthreads();
    if (tid < Cq){
      float s = 0.f;
      #pragma unroll
      for (int w2=0;w2<8;w2++) s += pen[w2*64 + tid];
      Sen[tid] = sqrtf(s);
    }
    __syncthreads();
    // grad + us
    {
      float uss = 0.f;
      #pragma unroll
      for (int ct=0;ct<4;ct++){
        #pragma unroll
        for (int r=0;r<4;r++){
          int c = ct*16 + q*4 + r;
          float en = Sen[c];
          float dv = Sd[c*132 + h];
          float e = err[ct][r];
          float g = (en > dv) ? dv*e*__builtin_amdgcn_rcpf(en+1e-9f) : e;
          err[ct][r] = g;
          uss += g;
        }
      }
      uss += __shfl_xor(uss,16,64);
      uss += __shfl_xor(uss,32,64);
      if (q==0) Sus[h] = uss*(1.f/64.f);
    }
    __syncthreads();
    // ---- state updates (all-register) ----
    {
      float aw = (Sabp[0]+Sabp[1])*(1.f/128.f);
      float ew = (Sebp[0]+Sebp[1])*(1.f/128.f);
      float4 s0[4], s1[4];
      #pragma unroll
      for (int ks=0;ks<4;ks++){
        s0[ks] = *(const float4*)&Sus[ks*32 + q*8];
        s1[ks] = *(const float4*)&Sus[ks*32 + q*8 + 4];
      }
      #pragma unroll
      for (int tt=0;tt<2;tt++){
        int m = (2*wv+tt)*16 + n;
        float amm = Sam[m];
        float eam = ew*amm;
        float part = 0.f;
        #pragma unroll
        for (int ks=0;ks<4;ks++){
          #pragma unroll
          for (int j=0;j<4;j++){
            float su0 = s0[ks][j], su1 = s1[ks][j];
            w1m[tt][ks][j]   = aw*w1m[tt][ks][j]   - eam*su0;
            w1m[tt][ks][j+4] = aw*w1m[tt][ks][j+4] - eam*su1;
            float nw0 = aw*w2t[tt][ks][j]   - ew*su0*amm;
            float nw1 = aw*w2t[tt][ks][j+4] - ew*su1*amm;
            w2t[tt][ks][j] = nw0;  w2t[tt][ks][j+4] = nw1;
            part += su0*nw0 + su1*nw1;
          }
        }
        part += __shfl_xor(part, 16, 64);
        part += __shfl_xor(part, 32, 64);
        b1reg[tt] = aw*b1reg[tt] - ew*part;   // b1u = us . nW2[:,m]
      }
      float ush = Sus[h];
      float eus = ew*ush;
      #pragma unroll
      for (int ks2=0;ks2<8;ks2++){
        float4 a0 = *(const float4*)&Sam[ks2*32 + q*8];
        float4 a1 = *(const float4*)&Sam[ks2*32 + q*8 + 4];
        #pragma unroll
        for (int j=0;j<4;j++){
          w2m[ks2][j]   = aw*w2m[ks2][j]   - eus*a0[j];
          w2m[ks2][j+4] = aw*w2m[ks2][j+4] - eus*a1[j];
        }
      }
      b2reg = Sab[h]*b2reg - Seb[h]*ush;
    }
  }
}

extern "C" void kernel_launch(void* const* d_in, const int* in_sizes, int n_in,
                              void* d_out, int out_size, void* d_ws, size_t ws_size,
                              hipStream_t stream)
{
  const float* x    = (const float*)d_in[0];
  // d_in[1]=Wq, d_in[14],[15]=qn_g/qn_b: dead (q path unused by output).
  const float* Wk   = (const float*)d_in[2];
  const float* Wv   = (const float*)d_in[3];
  const float* Wo   = (const float*)d_in[4];
  const float* Wg   = (const float*)d_in[5];
  const float* We1  = (const float*)d_in[6];
  const float* We2  = (const float*)d_in[7];
  const float* Wd1  = (const float*)d_in[8];
  const float* Wd2  = (const float*)d_in[9];
  const float* Wa1  = (const float*)d_in[10];
  const float* Wa2  = (const float*)d_in[11];
  const float* conv_w = (const float*)d_in[12];
  const float* conv_b = (const float*)d_in[13];
  const float* kn_g = (const float*)d_in[16];
  const float* kn_b = (const float*)d_in[17];
  const float* mW1  = (const float*)d_in[18];
  const float* mb1  = (const float*)d_in[19];
  const float* mW2  = (const float*)d_in[20];
  const float* mb2  = (const float*)d_in[21];
  float* out = (float*)d_out;

  float* ws = (float*)d_ws;
  size_t o = 0;
  float* k_raw = ws + o; o += (size_t)BSq*Hq;
  float* v_raw = ws + o; o += (size_t)BSq*Hq;
  float* te    = ws + o; o += (size_t)BSq*Rq;
  float* td    = ws + o; o += (size_t)BSq*Rq;
  float* ta    = ws + o; o += (size_t)BSq*Rq;
  float* glog  = ws + o; o += (size_t)BSq*Dq;
  float* etab  = ws + o; o += (size_t)BSq*Hq;
  float* deltab= ws + o; o += (size_t)BSq*Hq;
  float* alphab= ws + o; o += (size_t)BSq*Hq;
  float* k_ln  = ws + o; o += (size_t)BSq*Hq;
  float* v_c   = ws + o; o += (size_t)BSq*Hq;
  float* comb  = ws + o; o += (size_t)BSq*Hq;
  unsigned short* us = (unsigned short*)(ws + o);
  size_t u = 0;
  unsigned short *WkTh = us+u; u += (size_t)Hq*Dq;  unsigned short *WkTl = us+u; u += (size_t)Hq*Dq;
  unsigned short *WvTh = us+u; u += (size_t)Hq*Dq;  unsigned short *WvTl = us+u; u += (size_t)Hq*Dq;
  unsigned short *We1Th= us+u; u += (size_t)Rq*Dq;  unsigned short *We1Tl= us+u; u += (size_t)Rq*Dq;
  unsigned short *Wd1Th= us+u; u += (size_t)Rq*Dq;  unsigned short *Wd1Tl= us+u; u += (size_t)Rq*Dq;
  unsigned short *Wa1Th= us+u; u += (size_t)Rq*Dq;  unsigned short *Wa1Tl= us+u; u += (size_t)Rq*Dq;
  unsigned short *WgTh = us+u; u += (size_t)Dq*Dq;  unsigned short *WgTl = us+u; u += (size_t)Dq*Dq;
  unsigned short *We2Th= us+u; u += (size_t)Hq*Rq;  unsigned short *We2Tl= us+u; u += (size_t)Hq*Rq;
  unsigned short *Wd2Th= us+u; u += (size_t)Hq*Rq;  unsigned short *Wd2Tl= us+u; u += (size_t)Hq*Rq;
  unsigned short *Wa2Th= us+u; u += (size_t)Hq*Rq;  unsigned short *Wa2Tl= us+u; u += (size_t)Hq*Rq;
  unsigned short *WoTh = us+u; u += (size_t)Dq*Hq;  unsigned short *WoTl = us+u; u += (size_t)Dq*Hq;

  splitT<<<(Hq*Dq+255)/256, 256, 0, stream>>>(Wk,  WkTh,  WkTl,  Dq, Hq);
  splitT<<<(Hq*Dq+255)/256, 256, 0, stream>>>(Wv,  WvTh,  WvTl,  Dq, Hq);
  splitT<<<(Rq*Dq+255)/256, 256, 0, stream>>>(We1, We1Th, We1Tl, Dq, Rq);
  splitT<<<(Rq*Dq+255)/256, 256, 0, stream>>>(Wd1, Wd1Th, Wd1Tl, Dq, Rq);
  splitT<<<(Rq*Dq+255)/256, 256, 0, stream>>>(Wa1, Wa1Th, Wa1Tl, Dq, Rq);
  splitT<<<(Dq*Dq+255)/256, 256, 0, stream>>>(Wg,  WgTh,  WgTl,  Dq, Dq);
  splitT<<<(Hq*Rq+255)/256, 256, 0, stream>>>(We2, We2Th, We2Tl, Rq, Hq);
  splitT<<<(Hq*Rq+255)/256, 256, 0, stream>>>(Wd2, Wd2Th, Wd2Tl, Rq, Hq);
  splitT<<<(Hq*Rq+255)/256, 256, 0, stream>>>(Wa2, Wa2Th, Wa2Tl, Rq, Hq);
  splitT<<<(Dq*Hq+255)/256, 256, 0, stream>>>(Wo,  WoTh,  WoTl,  Hq, Dq);

  dim3 blk(256);
  gemm_bf3<128,0><<<dim3(1, BSq/128), blk, 0, stream>>>(x, WkTh, WkTl, k_raw, nullptr, Hq, Dq);
  gemm_bf3<128,0><<<dim3(1, BSq/128), blk, 0, stream>>>(x, WvTh, WvTl, v_raw, nullptr, Hq, Dq);
  gemm_bf3<64,0> <<<dim3(1, BSq/128), blk, 0, stream>>>(x, We1Th, We1Tl, te, nullptr, Rq, Dq);
  gemm_bf3<64,0> <<<dim3(1, BSq/128), blk, 0, stream>>>(x, Wd1Th, Wd1Tl, td, nullptr, Rq, Dq);
  gemm_bf3<64,0> <<<dim3(1, BSq/128), blk, 0, stream>>>(x, Wa1Th, Wa1Tl, ta, nullptr, Rq, Dq);
  gemm_bf3<128,1><<<dim3(1, BSq/128), blk, 0, stream>>>(te, We2Th, We2Tl, etab,   nullptr, Hq, Rq);
  gemm_bf3<128,1><<<dim3(1, BSq/128), blk, 0, stream>>>(td, Wd2Th, Wd2Tl, deltab, nullptr, Hq, Rq);
  gemm_bf3<128,2><<<dim3(1, BSq/128), blk, 0, stream>>>(ta, Wa2Th, Wa2Tl, alphab, nullptr, Hq, Rq);
  conv_ln_kernel<<<dim3(Sq, Bq, 2), dim3(128), 0, stream>>>(
      k_raw, v_raw, conv_w, conv_b, kn_g, kn_b, k_ln, v_c);
  // fused: scan (blocks 0..3) + Wg GEMM (blocks 4..1027) co-scheduled
  fused_scan_wg<<<dim3(4 + (BSq/128)*(Dq/128)), dim3(512), 0, stream>>>(
      k_ln, v_c, etab, deltab, alphab, mW1, mb1, mW2, mb2, comb,
      x, WgTh, WgTl, glog);
  gemm_bf3<128,3><<<dim3(Dq/128, BSq/128), blk, 0, stream>>>(comb, WoTh, WoTl, out, glog, Dq, Hq);
}